// Round 5
// baseline (615.681 us; speedup 1.0000x reference)
//
#include <hip/hip_runtime.h>
#include <cfloat>
#include <cmath>

#define NB 2
#define NC 34
#define NH 512
#define NW 1024
#define HWSZ (NH*NW)          // 524288 = 2^19
#define TK 200
#define CAPC 49152            // >= plausible 7x7 local-maxima count
#define CHUNK 8192            // LDS sort chunk (64KB)
#define ACH 1024              // pixels per block for aggregation kernels
#define ZWORDS (8 + NB*TK*NC + NB*TK)   // ccnt + segcnt + probsum, contiguous

typedef unsigned long long u64;

// ---------------- K1: fused zero + softmax(argmax,max,online-denom) + vote ----------------
// grid = NB*NH blocks (one image row per block), 256 threads, 4 pixels/thread.
__global__ __launch_bounds__(256) void k_segvote(const float* __restrict__ logits,
                                                 const float* __restrict__ reg,
                                                 float* __restrict__ segmap_out,
                                                 int* __restrict__ segid,
                                                 float* __restrict__ mArr,
                                                 float* __restrict__ dArr,
                                                 float* __restrict__ vote,
                                                 int* __restrict__ zreg) {
    int tid = threadIdx.x;
    int blk = blockIdx.x;
    int zi = blk * 256 + tid;
    if (zi < ZWORDS) zreg[zi] = 0;        // zero ccnt/segcnt/probsum (first 56 blocks)
    int b = blk >> 9;
    int y = blk & 511;
    int xb = tid << 2;                    // pixels x = xb..xb+3
    size_t rowoff = (size_t)y * NW + xb;

    // ---- seg: streaming float4 loads, exact argmax (first-index), online denom ----
    const float* lb = logits + (size_t)b * NC * HWSZ + rowoff;
    float m0=-FLT_MAX,m1=-FLT_MAX,m2=-FLT_MAX,m3=-FLT_MAX;
    float d0=0.f,d1=0.f,d2=0.f,d3=0.f;
    int c0=0,c1=0,c2=0,c3=0;
#pragma unroll
    for (int c = 0; c < NC; c++) {
        float4 v = *(const float4*)(lb + (size_t)c * HWSZ);
        if (v.x > m0) { d0 = d0*expf(m0-v.x)+1.f; m0=v.x; c0=c; } else d0 += expf(v.x-m0);
        if (v.y > m1) { d1 = d1*expf(m1-v.y)+1.f; m1=v.y; c1=c; } else d1 += expf(v.y-m1);
        if (v.z > m2) { d2 = d2*expf(m2-v.z)+1.f; m2=v.z; c2=c; } else d2 += expf(v.z-m2);
        if (v.w > m3) { d3 = d3*expf(m3-v.w)+1.f; m3=v.w; c3=c; } else d3 += expf(v.w-m3);
    }
    int p = b * HWSZ + (int)rowoff;
    *(float4*)(segmap_out + p) = make_float4((float)c0,(float)c1,(float)c2,(float)c3);
    *(int4*)(segid + p) = make_int4(c0,c1,c2,c3);
    *(float4*)(mArr + p) = make_float4(m0,m1,m2,m3);
    *(float4*)(dArr + p) = make_float4(d0,d1,d2,d3);

    // ---- vote: exact f32 order (i asc, j asc, circle-mask ranges), register row reuse ----
    const float* r0 = reg + (size_t)b * 2 * HWSZ;
    const float* r1 = r0 + HWSZ;
    const int lo[11] = {5,2,1,1,1,0,1,1,1,2,5};
    const int hi[11] = {5,8,9,9,9,10,9,9,9,8,5};
    float a0=0.f,a1=0.f,a2=0.f,a3=0.f;
#pragma unroll
    for (int i = 0; i < 11; i++) {
        int yy = y + i - 5;
        bool rowin = (yy >= 0) && (yy < NH);
        const float* p0 = r0 + (size_t)(rowin ? yy : 0) * NW;
        const float* p1 = r1 + (size_t)(rowin ? yy : 0) * NW;
        float s0[14], s1[14];
#pragma unroll
        for (int t = 0; t < 14; t++) {
            int xx = xb - 5 + t;
            bool in = rowin && (xx >= 0) && (xx < NW);
            s0[t] = in ? p0[xx] : 0.f;    // zero-padding per reference
            s1[t] = in ? p1[xx] : 0.f;
        }
        float di = (float)(i - 5);
#pragma unroll
        for (int j = 0; j < 11; j++) {
            if (j < lo[i] || j > hi[i]) continue;   // compile-time mask
            float dj = (float)(j - 5);
            float dx, dy, ss;
            dx = __fsub_rn(dj, s0[j+0]); dy = __fsub_rn(di, s1[j+0]);
            ss = __fadd_rn(__fmul_rn(dx,dx), __fmul_rn(dy,dy));
            a0 = __fadd_rn(a0, sqrtf(ss));
            dx = __fsub_rn(dj, s0[j+1]); dy = __fsub_rn(di, s1[j+1]);
            ss = __fadd_rn(__fmul_rn(dx,dx), __fmul_rn(dy,dy));
            a1 = __fadd_rn(a1, sqrtf(ss));
            dx = __fsub_rn(dj, s0[j+2]); dy = __fsub_rn(di, s1[j+2]);
            ss = __fadd_rn(__fmul_rn(dx,dx), __fmul_rn(dy,dy));
            a2 = __fadd_rn(a2, sqrtf(ss));
            dx = __fsub_rn(dj, s0[j+3]); dy = __fsub_rn(di, s1[j+3]);
            ss = __fadd_rn(__fmul_rn(dx,dx), __fmul_rn(dy,dy));
            a3 = __fadd_rn(a3, sqrtf(ss));
        }
    }
    float4 vv;
    vv.x = __fsub_rn(-__fdiv_rn(a0, 81.0f), 1.0f);
    vv.y = __fsub_rn(-__fdiv_rn(a1, 81.0f), 1.0f);
    vv.z = __fsub_rn(-__fdiv_rn(a2, 81.0f), 1.0f);
    vv.w = __fsub_rn(-__fdiv_rn(a3, 81.0f), 1.0f);
    *(float4*)(vote + p) = vv;
}

// ---------------- K3: 7x7 max pool via column maxes, keep, key compaction ----------------
__global__ __launch_bounds__(256) void k_pool(const float* __restrict__ vote,
                                              float* __restrict__ cmap_out,
                                              u64* __restrict__ keys,
                                              int* __restrict__ ccnt,
                                              float thr_keep) {
    int tid = threadIdx.x;
    int blk = blockIdx.x;
    int b = blk >> 9;
    int y = blk & 511;
    int xb = tid << 2;
    const float* vb = vote + (size_t)b * HWSZ;
    float cm[10];
#pragma unroll
    for (int t = 0; t < 10; t++) cm[t] = -INFINITY;
#pragma unroll
    for (int dy = -3; dy <= 3; dy++) {
        int yy = y + dy;
        if (yy < 0 || yy >= NH) continue;
        const float* row = vb + (size_t)yy * NW;
#pragma unroll
        for (int t = 0; t < 10; t++) {
            int xx = xb - 3 + t;
            if (xx >= 0 && xx < NW) cm[t] = fmaxf(cm[t], row[xx]);
        }
    }
    int pix = y * NW + xb;
    float4 v4 = *(const float4*)(vb + pix);
    float vv[4] = {v4.x, v4.y, v4.z, v4.w};
    float cmap[4];
#pragma unroll
    for (int k = 0; k < 4; k++) {
        float mx = cm[k];
#pragma unroll
        for (int u = 1; u < 7; u++) mx = fmaxf(mx, cm[k+u]);
        bool keep = (mx == vv[k]) && (vv[k] > thr_keep);
        cmap[k] = keep ? vv[k] : 0.0f;
        if (keep) {
            int pos = atomicAdd(&ccnt[b], 1);
            if (pos < CAPC) {
                unsigned u = __float_as_uint(vv[k]);
                unsigned ou = ((int)u < 0) ? ~u : (u | 0x80000000u);
                keys[(size_t)b * CAPC + pos] = ((u64)ou << 19) | (u64)(HWSZ - 1 - (pix + k));
            }
        }
    }
    *(float4*)(cmap_out + b * HWSZ + pix) = make_float4(cmap[0],cmap[1],cmap[2],cmap[3]);
}

// Descending bitonic sort of a[0..np2) in LDS. Keys unique (or 0) -> deterministic.
__device__ inline void bitonic_desc(u64* a, int np2, int tid, int T) {
    for (int k = 2; k <= np2; k <<= 1) {
        for (int j = k >> 1; j > 0; j >>= 1) {
            for (int i = tid; i < np2; i += T) {
                int ixj = i ^ j;
                if (ixj > i) {
                    u64 x = a[i], y = a[ixj];
                    bool up = ((i & k) == 0);
                    if (up ? (x < y) : (x > y)) { a[i] = y; a[ixj] = x; }
                }
            }
            __syncthreads();
        }
    }
}

// ---------------- K4: top-200 via LDS bitonic sort ----------------
__global__ __launch_bounds__(1024) void k_topk(const u64* __restrict__ keys_g,
                                               const int* __restrict__ ccnt,
                                               float* __restrict__ cxArr,
                                               float* __restrict__ cyArr,
                                               float* __restrict__ out_centers,
                                               float* __restrict__ out_topvals) {
    __shared__ u64 sk[CHUNK];
    __shared__ u64 cur[512];
    const int T = 1024;
    int b = blockIdx.x;
    int tid = threadIdx.x;
    int n = ccnt[b];
    if (n > CAPC) n = CAPC;
    const u64* Kg = keys_g + (size_t)b * CAPC;
    int nch = (n + CHUNK - 1) / CHUNK;
    if (nch < 1) nch = 1;
    if (tid < 512) cur[tid] = 0;
    __syncthreads();
    for (int ch = 0; ch < nch; ch++) {
        int off = ch * CHUNK;
        int len = n - off; if (len < 0) len = 0; if (len > CHUNK) len = CHUNK;
        int np2 = 256; while (np2 < len) np2 <<= 1;
        for (int c = tid; c < np2; c += T) sk[c] = (c < len) ? Kg[off + c] : 0;
        __syncthreads();
        bitonic_desc(sk, np2, tid, T);
        if (ch == 0) {
            if (tid < TK) cur[tid] = sk[tid];
            __syncthreads();
        } else {
            if (tid < TK) cur[TK + tid] = sk[tid];
            else if (tid < 512) { if (tid >= 2 * TK) cur[tid] = 0; }
            __syncthreads();
            bitonic_desc(cur, 512, tid, T);
        }
    }
    if (tid < TK) {
        u64 w = cur[tid];
        bool valid = (w != 0ULL);
        unsigned ou = (unsigned)(w >> 19);
        unsigned ub = (ou & 0x80000000u) ? (ou & 0x7FFFFFFFu) : ~ou;
        float v = __uint_as_float(ub);
        int pix = valid ? (int)(HWSZ - 1 - (int)(w & 0x7FFFFULL)) : 0x7fffffff;
        int ys = pix >> 10;
        int xs = pix & (NW - 1);
        cxArr[b * TK + tid] = valid ? (float)xs : 1e9f;
        cyArr[b * TK + tid] = valid ? (float)ys : 1e9f;
        out_centers[(b * TK + tid) * 2 + 0] = (float)ys;
        out_centers[(b * TK + tid) * 2 + 1] = (float)xs;
        out_topvals[b * TK + tid] = valid ? v : -INFINITY;
    }
}

// ---------------- K5: instance assignment + LDS-aggregated seg_counts ----------------
__global__ __launch_bounds__(256) void k_assign(const float* __restrict__ reg,
                                                const int* __restrict__ segid,
                                                const float* __restrict__ cxArr,
                                                const float* __restrict__ cyArr,
                                                float* __restrict__ out_inst,
                                                int* __restrict__ instid,
                                                int* __restrict__ segcnt) {
    __shared__ float scx[TK];
    __shared__ float scy[TK];
    __shared__ int lcnt[TK * NC];
    int tid = threadIdx.x;
    int base = blockIdx.x * ACH;
    int b = base >> 19;
    if (tid < TK) {
        scx[tid] = cxArr[b * TK + tid];
        scy[tid] = cyArr[b * TK + tid];
    }
    for (int t = tid; t < TK * NC; t += 256) lcnt[t] = 0;
    __syncthreads();
    const float* r0 = reg + (size_t)b * 2 * HWSZ;
    const float* r1 = r0 + HWSZ;
    float px[4], py[4], bd[4];
    int bk[4];
#pragma unroll
    for (int it = 0; it < 4; it++) {
        int pix = (base & (HWSZ - 1)) + it * 256 + tid;
        int y = pix >> 10;
        int x = pix & (NW - 1);
        px[it] = __fsub_rn((float)(x + 1), r0[pix]);
        py[it] = __fsub_rn((float)(y + 1), r1[pix]);
        bd[it] = INFINITY; bk[it] = 0;
    }
#pragma unroll 4
    for (int k = 0; k < TK; k++) {
        float cx = scx[k];
        float cy = scy[k];
#pragma unroll
        for (int it = 0; it < 4; it++) {
            float dx = __fsub_rn(px[it], cx);
            float dy = __fsub_rn(py[it], cy);
            float d2 = __fadd_rn(__fmul_rn(dx, dx), __fmul_rn(dy, dy));
            if (d2 < bd[it]) { bd[it] = d2; bk[it] = k; }
        }
    }
#pragma unroll
    for (int it = 0; it < 4; it++) {
        int p = base + it * 256 + tid;
        int cls = segid[p];
        int thing = (cls >= 24) ? 1 : 0;
        int inst = (bk[it] + 1) * thing;
        out_inst[p] = (float)inst;
        instid[p] = inst;
        if (inst) atomicAdd(&lcnt[bk[it] * NC + cls], 1);
    }
    __syncthreads();
    for (int t = tid; t < TK * NC; t += 256) {
        int v = lcnt[t];
        if (v) atomicAdd(&segcnt[b * TK * NC + t], v);
    }
}

// ---------------- K6: per-instance class argmax + size ----------------
__global__ __launch_bounds__(256) void k_stats(const int* __restrict__ segcnt,
                                               float* __restrict__ out_icls,
                                               float* __restrict__ out_isize,
                                               int* __restrict__ icls,
                                               int* __restrict__ isize) {
    int t = blockIdx.x * 256 + threadIdx.x;
    if (t >= NB * TK) return;
    const int* row = segcnt + (size_t)t * NC;
    int total = 0; int bc = 0; int bv = -1;
#pragma unroll
    for (int c = 0; c < NC; c++) {
        int v = row[c];
        total += v;
        if (v > bv) { bv = v; bc = c; }
    }
    out_icls[t] = (float)bc;
    out_isize[t] = (float)total;
    icls[t] = bc;
    isize[t] = total;
}

// ---------------- K7: prob sum of selected class, LDS-aggregated ----------------
__global__ __launch_bounds__(256) void k_probsum(const float* __restrict__ logits,
                                                 const int* __restrict__ instid,
                                                 const float* __restrict__ mArr,
                                                 const float* __restrict__ dArr,
                                                 const int* __restrict__ icls,
                                                 float* __restrict__ probsum) {
    __shared__ float lps[TK];
    int tid = threadIdx.x;
    int base = blockIdx.x * ACH;
    int b = base >> 19;
    for (int t = tid; t < TK; t += 256) lps[t] = 0.f;
    __syncthreads();
#pragma unroll
    for (int it = 0; it < 4; it++) {
        int p = base + it * 256 + tid;
        int inst = instid[p];
        if (inst) {
            int pix = p & (HWSZ - 1);
            int c = icls[b * TK + inst - 1];
            float xv = logits[(size_t)(b * NC + c) * HWSZ + pix];
            float pr = __fdiv_rn(expf(__fsub_rn(xv, mArr[p])), dArr[p]);
            atomicAdd(&lps[inst - 1], pr);
        }
    }
    __syncthreads();
    for (int t = tid; t < TK; t += 256) {
        float s = lps[t];
        if (s != 0.f) atomicAdd(&probsum[b * TK + t], s);
    }
}

// ---------------- K8: finalize inst_seg_prob ----------------
__global__ __launch_bounds__(256) void k_final(const float* __restrict__ probsum,
                                               const int* __restrict__ isize,
                                               float* __restrict__ out_iprob) {
    int t = blockIdx.x * 256 + threadIdx.x;
    if (t >= NB * TK) return;
    float s = probsum[t];
    float sz = (float)isize[t];
    out_iprob[t] = __fdiv_rn(s, fmaxf(sz, 1.0f));
}

// Host: replicate _circle_constants threshold exactly (NumPy pairwise sum, f32)
static float compute_thr_keep() {
    float cdm[121];
    int t = 0;
    for (int i = 0; i < 11; i++) {
        for (int j = 0; j < 11; j++) {
            float ox = (float)(j - 5), oy = (float)(i - 5);
            float cd = sqrtf(ox * ox + oy * oy);
            float cm = (cd <= 5.0f) ? 1.0f : 0.0f;
            cdm[t++] = cd * cm;
        }
    }
    float r[8];
    for (int k = 0; k < 8; k++) r[k] = cdm[k];
    int i = 8;
    for (; i < 121 - (121 % 8); i += 8)
        for (int k = 0; k < 8; k++) r[k] += cdm[i + k];
    float res = ((r[0] + r[1]) + (r[2] + r[3])) + ((r[4] + r[5]) + (r[6] + r[7]));
    for (; i < 121; i++) res += cdm[i];
    float thr = res / 81.0f;
    double kt = -(double)thr - 1.0;
    return (float)kt;
}

extern "C" void kernel_launch(void* const* d_in, const int* in_sizes, int n_in,
                              void* d_out, int out_size, void* d_ws, size_t ws_size,
                              hipStream_t stream) {
    const float* logits = (const float*)d_in[0];
    const float* reg    = (const float*)d_in[2];
    float* out = (float*)d_out;

    // output layout (all f32)
    float* o_inst    = out;                       // B*HW
    float* o_seg     = out + 1048576;             // B*HW
    float* o_centers = out + 2097152;             // B*TK*2
    float* o_topvals = out + 2097952;             // B*TK
    float* o_icls    = out + 2098352;             // B*TK
    float* o_iprob   = out + 2098752;             // B*TK
    float* o_isize   = out + 2099152;             // B*TK
    float* o_cmap    = out + 2099552;             // B*HW

    // workspace: keys (8B aligned) first, then contiguous zero-region, then rest
    u64* keys = (u64*)d_ws;                                   // NB*CAPC
    float* wsf = (float*)(keys + (size_t)NB * CAPC);
    size_t o = 0;
    int*   zreg   = (int*)(wsf + o); o += ZWORDS;             // [ccnt(8) | segcnt | probsum]
    int*   ccnt   = zreg;
    int*   segcnt = zreg + 8;
    float* probsum= (float*)(zreg + 8 + NB * TK * NC);
    float* vote   = wsf + o; o += (size_t)NB * HWSZ;
    float* mArr   = wsf + o; o += (size_t)NB * HWSZ;
    float* dArr   = wsf + o; o += (size_t)NB * HWSZ;
    int*   segid  = (int*)(wsf + o); o += (size_t)NB * HWSZ;
    int*   instid = (int*)(wsf + o); o += (size_t)NB * HWSZ;
    float* cxArr  = wsf + o; o += NB * TK;
    float* cyArr  = wsf + o; o += NB * TK;
    int*   icls   = (int*)(wsf + o); o += NB * TK;
    int*   isize  = (int*)(wsf + o); o += NB * TK;

    float thr_keep = compute_thr_keep();

    int gridRow = NB * NH;             // 1024: one image row per block, 4 px/thread
    int gridAgg = (NB * HWSZ) / ACH;   // 1024

    k_segvote<<<gridRow, 256, 0, stream>>>(logits, reg, o_seg, segid, mArr, dArr, vote, zreg);
    k_pool<<<gridRow, 256, 0, stream>>>(vote, o_cmap, keys, ccnt, thr_keep);
    k_topk<<<NB, 1024, 0, stream>>>(keys, ccnt, cxArr, cyArr, o_centers, o_topvals);
    k_assign<<<gridAgg, 256, 0, stream>>>(reg, segid, cxArr, cyArr, o_inst, instid, segcnt);
    k_stats<<<(NB * TK + 255) / 256, 256, 0, stream>>>(segcnt, o_icls, o_isize, icls, isize);
    k_probsum<<<gridAgg, 256, 0, stream>>>(logits, instid, mArr, dArr, icls, probsum);
    k_final<<<(NB * TK + 255) / 256, 256, 0, stream>>>(probsum, isize, o_iprob);
}

// Round 6
// 536.721 us; speedup vs baseline: 1.1471x; 1.1471x over previous
//
#include <hip/hip_runtime.h>
#include <cfloat>
#include <cmath>

#define NB 2
#define NC 34
#define NH 512
#define NW 1024
#define HWSZ (NH*NW)          // 524288 = 2^19
#define TK 200
#define CAPC 49152            // >= plausible 7x7 local-maxima count
#define CHUNK 8192            // LDS sort chunk (64KB)
#define ACH 1024              // pixels per block for aggregation kernels
#define ZWORDS (8 + NB*TK*NC + NB*TK)   // ccnt + segcnt + probsum, contiguous

typedef unsigned long long u64;

// ---------------- K1: softmax argmax + max + denom (two-pass exact) + zero-fold ----------------
__global__ __launch_bounds__(256) void k_seg(const float* __restrict__ logits,
                                             float* __restrict__ segmap_out,
                                             int* __restrict__ segid,
                                             float* __restrict__ mArr,
                                             float* __restrict__ dArr,
                                             int* __restrict__ zreg) {
    int p = blockIdx.x * 256 + threadIdx.x;
    if (p < ZWORDS) zreg[p] = 0;          // zero ccnt/segcnt/probsum (first 55 blocks)
    if (p >= NB * HWSZ) return;
    int b = p >> 19;
    int pix = p & (HWSZ - 1);
    const float* base = logits + (size_t)b * NC * HWSZ + pix;
    float v[NC];
#pragma unroll
    for (int c = 0; c < NC; c++) v[c] = base[(size_t)c * HWSZ];
    float m = -FLT_MAX; int bc = 0;
#pragma unroll
    for (int c = 0; c < NC; c++) { if (v[c] > m) { m = v[c]; bc = c; } }
    float den = 0.f;
#pragma unroll
    for (int c = 0; c < NC; c++) den += expf(v[c] - m);
    segmap_out[p] = (float)bc;
    segid[p] = bc;
    mArr[p] = m;
    dArr[p] = den;
}

// ---------------- K2: vote map, 4 px/thread, register row window (exact f32 order) ----------------
__global__ __launch_bounds__(256) void k_vote(const float* __restrict__ reg,
                                              float* __restrict__ vote) {
    int tid = threadIdx.x;
    int blk = blockIdx.x;
    int b = blk >> 9;
    int y = blk & 511;
    int xb = tid << 2;                    // pixels x = xb..xb+3
    const float* r0 = reg + (size_t)b * 2 * HWSZ;
    const float* r1 = r0 + HWSZ;
    const int lo[11] = {5,2,1,1,1,0,1,1,1,2,5};
    const int hi[11] = {5,8,9,9,9,10,9,9,9,8,5};
    float a0=0.f,a1=0.f,a2=0.f,a3=0.f;
#pragma unroll
    for (int i = 0; i < 11; i++) {
        int yy = y + i - 5;
        bool rowin = (yy >= 0) && (yy < NH);
        const float* p0 = r0 + (size_t)(rowin ? yy : 0) * NW;
        const float* p1 = r1 + (size_t)(rowin ? yy : 0) * NW;
        float s0[14], s1[14];
#pragma unroll
        for (int t = 0; t < 14; t++) {
            int xx = xb - 5 + t;
            bool in = rowin && (xx >= 0) && (xx < NW);
            s0[t] = in ? p0[xx] : 0.f;    // zero-padding per reference
            s1[t] = in ? p1[xx] : 0.f;
        }
        float di = (float)(i - 5);
#pragma unroll
        for (int j = 0; j < 11; j++) {
            if (j < lo[i] || j > hi[i]) continue;   // compile-time circle mask
            float dj = (float)(j - 5);
            float dx, dy, ss;
            dx = __fsub_rn(dj, s0[j+0]); dy = __fsub_rn(di, s1[j+0]);
            ss = __fadd_rn(__fmul_rn(dx,dx), __fmul_rn(dy,dy));
            a0 = __fadd_rn(a0, sqrtf(ss));
            dx = __fsub_rn(dj, s0[j+1]); dy = __fsub_rn(di, s1[j+1]);
            ss = __fadd_rn(__fmul_rn(dx,dx), __fmul_rn(dy,dy));
            a1 = __fadd_rn(a1, sqrtf(ss));
            dx = __fsub_rn(dj, s0[j+2]); dy = __fsub_rn(di, s1[j+2]);
            ss = __fadd_rn(__fmul_rn(dx,dx), __fmul_rn(dy,dy));
            a2 = __fadd_rn(a2, sqrtf(ss));
            dx = __fsub_rn(dj, s0[j+3]); dy = __fsub_rn(di, s1[j+3]);
            ss = __fadd_rn(__fmul_rn(dx,dx), __fmul_rn(dy,dy));
            a3 = __fadd_rn(a3, sqrtf(ss));
        }
    }
    float4 vv;
    vv.x = __fsub_rn(-__fdiv_rn(a0, 81.0f), 1.0f);
    vv.y = __fsub_rn(-__fdiv_rn(a1, 81.0f), 1.0f);
    vv.z = __fsub_rn(-__fdiv_rn(a2, 81.0f), 1.0f);
    vv.w = __fsub_rn(-__fdiv_rn(a3, 81.0f), 1.0f);
    *(float4*)(vote + b * HWSZ + y * NW + xb) = vv;
}

// ---------------- K3: 7x7 max pool via column maxes, keep, key compaction ----------------
__global__ __launch_bounds__(256) void k_pool(const float* __restrict__ vote,
                                              float* __restrict__ cmap_out,
                                              u64* __restrict__ keys,
                                              int* __restrict__ ccnt,
                                              float thr_keep) {
    int tid = threadIdx.x;
    int blk = blockIdx.x;
    int b = blk >> 9;
    int y = blk & 511;
    int xb = tid << 2;
    const float* vb = vote + (size_t)b * HWSZ;
    float cm[10];
#pragma unroll
    for (int t = 0; t < 10; t++) cm[t] = -INFINITY;
#pragma unroll
    for (int dy = -3; dy <= 3; dy++) {
        int yy = y + dy;
        if (yy < 0 || yy >= NH) continue;
        const float* row = vb + (size_t)yy * NW;
#pragma unroll
        for (int t = 0; t < 10; t++) {
            int xx = xb - 3 + t;
            if (xx >= 0 && xx < NW) cm[t] = fmaxf(cm[t], row[xx]);
        }
    }
    int pix = y * NW + xb;
    float4 v4 = *(const float4*)(vb + pix);
    float vv[4] = {v4.x, v4.y, v4.z, v4.w};
    float cmap[4];
#pragma unroll
    for (int k = 0; k < 4; k++) {
        float mx = cm[k];
#pragma unroll
        for (int u = 1; u < 7; u++) mx = fmaxf(mx, cm[k+u]);
        bool keep = (mx == vv[k]) && (vv[k] > thr_keep);
        cmap[k] = keep ? vv[k] : 0.0f;
        if (keep) {
            int pos = atomicAdd(&ccnt[b], 1);
            if (pos < CAPC) {
                unsigned u = __float_as_uint(vv[k]);
                unsigned ou = ((int)u < 0) ? ~u : (u | 0x80000000u);
                keys[(size_t)b * CAPC + pos] = ((u64)ou << 19) | (u64)(HWSZ - 1 - (pix + k));
            }
        }
    }
    *(float4*)(cmap_out + b * HWSZ + pix) = make_float4(cmap[0],cmap[1],cmap[2],cmap[3]);
}

// Descending bitonic sort of a[0..np2) in LDS. Keys unique (or 0) -> deterministic.
__device__ inline void bitonic_desc(u64* a, int np2, int tid, int T) {
    for (int k = 2; k <= np2; k <<= 1) {
        for (int j = k >> 1; j > 0; j >>= 1) {
            for (int i = tid; i < np2; i += T) {
                int ixj = i ^ j;
                if (ixj > i) {
                    u64 x = a[i], y = a[ixj];
                    bool up = ((i & k) == 0);
                    if (up ? (x < y) : (x > y)) { a[i] = y; a[ixj] = x; }
                }
            }
            __syncthreads();
        }
    }
}

// ---------------- K4: top-200 via LDS bitonic sort ----------------
__global__ __launch_bounds__(1024) void k_topk(const u64* __restrict__ keys_g,
                                               const int* __restrict__ ccnt,
                                               float* __restrict__ cxArr,
                                               float* __restrict__ cyArr,
                                               float* __restrict__ out_centers,
                                               float* __restrict__ out_topvals) {
    __shared__ u64 sk[CHUNK];
    __shared__ u64 cur[512];
    const int T = 1024;
    int b = blockIdx.x;
    int tid = threadIdx.x;
    int n = ccnt[b];
    if (n > CAPC) n = CAPC;
    const u64* Kg = keys_g + (size_t)b * CAPC;
    int nch = (n + CHUNK - 1) / CHUNK;
    if (nch < 1) nch = 1;
    if (tid < 512) cur[tid] = 0;
    __syncthreads();
    for (int ch = 0; ch < nch; ch++) {
        int off = ch * CHUNK;
        int len = n - off; if (len < 0) len = 0; if (len > CHUNK) len = CHUNK;
        int np2 = 256; while (np2 < len) np2 <<= 1;
        for (int c = tid; c < np2; c += T) sk[c] = (c < len) ? Kg[off + c] : 0;
        __syncthreads();
        bitonic_desc(sk, np2, tid, T);
        if (ch == 0) {
            if (tid < TK) cur[tid] = sk[tid];
            __syncthreads();
        } else {
            if (tid < TK) cur[TK + tid] = sk[tid];
            else if (tid < 512) { if (tid >= 2 * TK) cur[tid] = 0; }
            __syncthreads();
            bitonic_desc(cur, 512, tid, T);
        }
    }
    if (tid < TK) {
        u64 w = cur[tid];
        bool valid = (w != 0ULL);
        unsigned ou = (unsigned)(w >> 19);
        unsigned ub = (ou & 0x80000000u) ? (ou & 0x7FFFFFFFu) : ~ou;
        float v = __uint_as_float(ub);
        int pix = valid ? (int)(HWSZ - 1 - (int)(w & 0x7FFFFULL)) : 0x7fffffff;
        int ys = pix >> 10;
        int xs = pix & (NW - 1);
        cxArr[b * TK + tid] = valid ? (float)xs : 1e9f;
        cyArr[b * TK + tid] = valid ? (float)ys : 1e9f;
        out_centers[(b * TK + tid) * 2 + 0] = (float)ys;
        out_centers[(b * TK + tid) * 2 + 1] = (float)xs;
        out_topvals[b * TK + tid] = valid ? v : -INFINITY;
    }
}

// ---------------- K5: instance assignment + LDS-aggregated seg_counts ----------------
__global__ __launch_bounds__(256) void k_assign(const float* __restrict__ reg,
                                                const int* __restrict__ segid,
                                                const float* __restrict__ cxArr,
                                                const float* __restrict__ cyArr,
                                                float* __restrict__ out_inst,
                                                int* __restrict__ instid,
                                                int* __restrict__ segcnt) {
    __shared__ float scx[TK];
    __shared__ float scy[TK];
    __shared__ int lcnt[TK * NC];
    int tid = threadIdx.x;
    int base = blockIdx.x * ACH;
    int b = base >> 19;
    if (tid < TK) {
        scx[tid] = cxArr[b * TK + tid];
        scy[tid] = cyArr[b * TK + tid];
    }
    for (int t = tid; t < TK * NC; t += 256) lcnt[t] = 0;
    __syncthreads();
    const float* r0 = reg + (size_t)b * 2 * HWSZ;
    const float* r1 = r0 + HWSZ;
    float px[4], py[4], bd[4];
    int bk[4];
#pragma unroll
    for (int it = 0; it < 4; it++) {
        int pix = (base & (HWSZ - 1)) + it * 256 + tid;
        int y = pix >> 10;
        int x = pix & (NW - 1);
        px[it] = __fsub_rn((float)(x + 1), r0[pix]);
        py[it] = __fsub_rn((float)(y + 1), r1[pix]);
        bd[it] = INFINITY; bk[it] = 0;
    }
#pragma unroll 4
    for (int k = 0; k < TK; k++) {
        float cx = scx[k];
        float cy = scy[k];
#pragma unroll
        for (int it = 0; it < 4; it++) {
            float dx = __fsub_rn(px[it], cx);
            float dy = __fsub_rn(py[it], cy);
            float d2 = __fadd_rn(__fmul_rn(dx, dx), __fmul_rn(dy, dy));
            if (d2 < bd[it]) { bd[it] = d2; bk[it] = k; }
        }
    }
#pragma unroll
    for (int it = 0; it < 4; it++) {
        int p = base + it * 256 + tid;
        int cls = segid[p];
        int thing = (cls >= 24) ? 1 : 0;
        int inst = (bk[it] + 1) * thing;
        out_inst[p] = (float)inst;
        instid[p] = inst;
        if (inst) atomicAdd(&lcnt[bk[it] * NC + cls], 1);
    }
    __syncthreads();
    for (int t = tid; t < TK * NC; t += 256) {
        int v = lcnt[t];
        if (v) atomicAdd(&segcnt[b * TK * NC + t], v);
    }
}

// ---------------- K6: per-instance class argmax + size ----------------
__global__ __launch_bounds__(256) void k_stats(const int* __restrict__ segcnt,
                                               float* __restrict__ out_icls,
                                               float* __restrict__ out_isize,
                                               int* __restrict__ icls,
                                               int* __restrict__ isize) {
    int t = blockIdx.x * 256 + threadIdx.x;
    if (t >= NB * TK) return;
    const int* row = segcnt + (size_t)t * NC;
    int total = 0; int bc = 0; int bv = -1;
#pragma unroll
    for (int c = 0; c < NC; c++) {
        int v = row[c];
        total += v;
        if (v > bv) { bv = v; bc = c; }
    }
    out_icls[t] = (float)bc;
    out_isize[t] = (float)total;
    icls[t] = bc;
    isize[t] = total;
}

// ---------------- K7: prob sum of selected class, LDS-aggregated ----------------
__global__ __launch_bounds__(256) void k_probsum(const float* __restrict__ logits,
                                                 const int* __restrict__ instid,
                                                 const float* __restrict__ mArr,
                                                 const float* __restrict__ dArr,
                                                 const int* __restrict__ icls,
                                                 float* __restrict__ probsum) {
    __shared__ float lps[TK];
    int tid = threadIdx.x;
    int base = blockIdx.x * ACH;
    int b = base >> 19;
    for (int t = tid; t < TK; t += 256) lps[t] = 0.f;
    __syncthreads();
#pragma unroll
    for (int it = 0; it < 4; it++) {
        int p = base + it * 256 + tid;
        int inst = instid[p];
        if (inst) {
            int pix = p & (HWSZ - 1);
            int c = icls[b * TK + inst - 1];
            float xv = logits[(size_t)(b * NC + c) * HWSZ + pix];
            float pr = __fdiv_rn(expf(__fsub_rn(xv, mArr[p])), dArr[p]);
            atomicAdd(&lps[inst - 1], pr);
        }
    }
    __syncthreads();
    for (int t = tid; t < TK; t += 256) {
        float s = lps[t];
        if (s != 0.f) atomicAdd(&probsum[b * TK + t], s);
    }
}

// ---------------- K8: finalize inst_seg_prob ----------------
__global__ __launch_bounds__(256) void k_final(const float* __restrict__ probsum,
                                               const int* __restrict__ isize,
                                               float* __restrict__ out_iprob) {
    int t = blockIdx.x * 256 + threadIdx.x;
    if (t >= NB * TK) return;
    float s = probsum[t];
    float sz = (float)isize[t];
    out_iprob[t] = __fdiv_rn(s, fmaxf(sz, 1.0f));
}

// Host: replicate _circle_constants threshold exactly (NumPy pairwise sum, f32)
static float compute_thr_keep() {
    float cdm[121];
    int t = 0;
    for (int i = 0; i < 11; i++) {
        for (int j = 0; j < 11; j++) {
            float ox = (float)(j - 5), oy = (float)(i - 5);
            float cd = sqrtf(ox * ox + oy * oy);
            float cm = (cd <= 5.0f) ? 1.0f : 0.0f;
            cdm[t++] = cd * cm;
        }
    }
    float r[8];
    for (int k = 0; k < 8; k++) r[k] = cdm[k];
    int i = 8;
    for (; i < 121 - (121 % 8); i += 8)
        for (int k = 0; k < 8; k++) r[k] += cdm[i + k];
    float res = ((r[0] + r[1]) + (r[2] + r[3])) + ((r[4] + r[5]) + (r[6] + r[7]));
    for (; i < 121; i++) res += cdm[i];
    float thr = res / 81.0f;
    double kt = -(double)thr - 1.0;
    return (float)kt;
}

extern "C" void kernel_launch(void* const* d_in, const int* in_sizes, int n_in,
                              void* d_out, int out_size, void* d_ws, size_t ws_size,
                              hipStream_t stream) {
    const float* logits = (const float*)d_in[0];
    const float* reg    = (const float*)d_in[2];
    float* out = (float*)d_out;

    // output layout (all f32)
    float* o_inst    = out;                       // B*HW
    float* o_seg     = out + 1048576;             // B*HW
    float* o_centers = out + 2097152;             // B*TK*2
    float* o_topvals = out + 2097952;             // B*TK
    float* o_icls    = out + 2098352;             // B*TK
    float* o_iprob   = out + 2098752;             // B*TK
    float* o_isize   = out + 2099152;             // B*TK
    float* o_cmap    = out + 2099552;             // B*HW

    // workspace: keys (8B aligned) first, then contiguous zero-region, then rest
    u64* keys = (u64*)d_ws;                                   // NB*CAPC
    float* wsf = (float*)(keys + (size_t)NB * CAPC);
    size_t o = 0;
    int*   zreg   = (int*)(wsf + o); o += ZWORDS;             // [ccnt(8) | segcnt | probsum]
    int*   ccnt   = zreg;
    int*   segcnt = zreg + 8;
    float* probsum= (float*)(zreg + 8 + NB * TK * NC);
    float* vote   = wsf + o; o += (size_t)NB * HWSZ;
    float* mArr   = wsf + o; o += (size_t)NB * HWSZ;
    float* dArr   = wsf + o; o += (size_t)NB * HWSZ;
    int*   segid  = (int*)(wsf + o); o += (size_t)NB * HWSZ;
    int*   instid = (int*)(wsf + o); o += (size_t)NB * HWSZ;
    float* cxArr  = wsf + o; o += NB * TK;
    float* cyArr  = wsf + o; o += NB * TK;
    int*   icls   = (int*)(wsf + o); o += NB * TK;
    int*   isize  = (int*)(wsf + o); o += NB * TK;

    float thr_keep = compute_thr_keep();

    int gridPix = (NB * HWSZ) / 256;   // 4096
    int gridRow = NB * NH;             // 1024: one image row per block, 4 px/thread
    int gridAgg = (NB * HWSZ) / ACH;   // 1024

    k_seg<<<gridPix, 256, 0, stream>>>(logits, o_seg, segid, mArr, dArr, zreg);
    k_vote<<<gridRow, 256, 0, stream>>>(reg, vote);
    k_pool<<<gridRow, 256, 0, stream>>>(vote, o_cmap, keys, ccnt, thr_keep);
    k_topk<<<NB, 1024, 0, stream>>>(keys, ccnt, cxArr, cyArr, o_centers, o_topvals);
    k_assign<<<gridAgg, 256, 0, stream>>>(reg, segid, cxArr, cyArr, o_inst, instid, segcnt);
    k_stats<<<(NB * TK + 255) / 256, 256, 0, stream>>>(segcnt, o_icls, o_isize, icls, isize);
    k_probsum<<<gridAgg, 256, 0, stream>>>(logits, instid, mArr, dArr, icls, probsum);
    k_final<<<(NB * TK + 255) / 256, 256, 0, stream>>>(probsum, isize, o_iprob);
}

// Round 7
// 491.662 us; speedup vs baseline: 1.2522x; 1.0916x over previous
//
#include <hip/hip_runtime.h>
#include <cfloat>
#include <cmath>

#define NB 2
#define NC 34
#define NH 512
#define NW 1024
#define HWSZ (NH*NW)          // 524288 = 2^19
#define TK 200
#define CAPC 49152            // >= plausible 7x7 local-maxima count
#define CHUNK 8192            // LDS sort chunk (64KB)
#define ACH 1024              // pixels per block for aggregation kernels
#define ZWORDS (8 + NB*TK*NC + NB*TK)   // ccnt + segcnt + probsum, contiguous

typedef unsigned long long u64;

// ---------------- K1: softmax argmax + max + denom (two-pass exact) + zero-fold ----------------
__global__ __launch_bounds__(256) void k_seg(const float* __restrict__ logits,
                                             float* __restrict__ segmap_out,
                                             int* __restrict__ segid,
                                             float* __restrict__ mArr,
                                             float* __restrict__ dArr,
                                             int* __restrict__ zreg) {
    int p = blockIdx.x * 256 + threadIdx.x;
    if (p < ZWORDS) zreg[p] = 0;          // zero ccnt/segcnt/probsum (first 55 blocks)
    if (p >= NB * HWSZ) return;
    int b = p >> 19;
    int pix = p & (HWSZ - 1);
    const float* base = logits + (size_t)b * NC * HWSZ + pix;
    float v[NC];
#pragma unroll
    for (int c = 0; c < NC; c++) v[c] = base[(size_t)c * HWSZ];
    float m = -FLT_MAX; int bc = 0;
#pragma unroll
    for (int c = 0; c < NC; c++) { if (v[c] > m) { m = v[c]; bc = c; } }
    float den = 0.f;
#pragma unroll
    for (int c = 0; c < NC; c++) den += expf(v[c] - m);
    segmap_out[p] = (float)bc;
    segid[p] = bc;
    mArr[p] = m;
    dArr[p] = den;
}

// ---------------- K2: vote map, 4 px/thread, one row-window live at a time ----------------
// VGPR control: i-loop NOT unrolled (one 28-reg window live), launch_bounds caps
// allocation at 128 VGPR (4 waves/EU). Exact f32 term order preserved: i asc,
// j asc within i, identical __f*_rn ops; (i,j) guard is wave-uniform.
__global__ __launch_bounds__(256, 4) void k_vote(const float* __restrict__ reg,
                                                 float* __restrict__ vote) {
    int tid = threadIdx.x;
    int blk = blockIdx.x;
    int b = blk >> 9;
    int y = blk & 511;
    int xb = tid << 2;                    // pixels x = xb..xb+3
    const float* r0 = reg + (size_t)b * 2 * HWSZ;
    const float* r1 = r0 + HWSZ;
    float a0=0.f,a1=0.f,a2=0.f,a3=0.f;
#pragma unroll 1
    for (int i = 0; i < 11; i++) {
        int d = i - 5;
        int ad = d < 0 ? -d : d;
        int w = (int)sqrtf((float)(25 - ad * ad));   // exact for {0,9,16,21,24,25}
        int lo = 5 - w, hi = 5 + w;                  // circle-mask j-range, wave-uniform
        int yy = y + d;
        bool rowin = (yy >= 0) && (yy < NH);
        const float* p0 = r0 + (size_t)(rowin ? yy : 0) * NW;
        const float* p1 = r1 + (size_t)(rowin ? yy : 0) * NW;
        float s0[14], s1[14];
#pragma unroll
        for (int t = 0; t < 14; t++) {
            int xx = xb - 5 + t;
            bool in = rowin && (xx >= 0) && (xx < NW);
            s0[t] = in ? p0[xx] : 0.f;    // zero-padding per reference
            s1[t] = in ? p1[xx] : 0.f;
        }
        float di = (float)d;
#pragma unroll
        for (int j = 0; j < 11; j++) {
            if (j < lo || j > hi) continue;          // uniform scalar branch
            float dj = (float)(j - 5);
            float dx, dy, ss;
            dx = __fsub_rn(dj, s0[j+0]); dy = __fsub_rn(di, s1[j+0]);
            ss = __fadd_rn(__fmul_rn(dx,dx), __fmul_rn(dy,dy));
            a0 = __fadd_rn(a0, sqrtf(ss));
            dx = __fsub_rn(dj, s0[j+1]); dy = __fsub_rn(di, s1[j+1]);
            ss = __fadd_rn(__fmul_rn(dx,dx), __fmul_rn(dy,dy));
            a1 = __fadd_rn(a1, sqrtf(ss));
            dx = __fsub_rn(dj, s0[j+2]); dy = __fsub_rn(di, s1[j+2]);
            ss = __fadd_rn(__fmul_rn(dx,dx), __fmul_rn(dy,dy));
            a2 = __fadd_rn(a2, sqrtf(ss));
            dx = __fsub_rn(dj, s0[j+3]); dy = __fsub_rn(di, s1[j+3]);
            ss = __fadd_rn(__fmul_rn(dx,dx), __fmul_rn(dy,dy));
            a3 = __fadd_rn(a3, sqrtf(ss));
        }
    }
    float4 vv;
    vv.x = __fsub_rn(-__fdiv_rn(a0, 81.0f), 1.0f);
    vv.y = __fsub_rn(-__fdiv_rn(a1, 81.0f), 1.0f);
    vv.z = __fsub_rn(-__fdiv_rn(a2, 81.0f), 1.0f);
    vv.w = __fsub_rn(-__fdiv_rn(a3, 81.0f), 1.0f);
    *(float4*)(vote + b * HWSZ + y * NW + xb) = vv;
}

// ---------------- K3: 7x7 max pool via column maxes, keep, key compaction ----------------
__global__ __launch_bounds__(256) void k_pool(const float* __restrict__ vote,
                                              float* __restrict__ cmap_out,
                                              u64* __restrict__ keys,
                                              int* __restrict__ ccnt,
                                              float thr_keep) {
    int tid = threadIdx.x;
    int blk = blockIdx.x;
    int b = blk >> 9;
    int y = blk & 511;
    int xb = tid << 2;
    const float* vb = vote + (size_t)b * HWSZ;
    float cm[10];
#pragma unroll
    for (int t = 0; t < 10; t++) cm[t] = -INFINITY;
#pragma unroll 1
    for (int dy = -3; dy <= 3; dy++) {
        int yy = y + dy;
        if (yy < 0 || yy >= NH) continue;
        const float* row = vb + (size_t)yy * NW;
#pragma unroll
        for (int t = 0; t < 10; t++) {
            int xx = xb - 3 + t;
            if (xx >= 0 && xx < NW) cm[t] = fmaxf(cm[t], row[xx]);
        }
    }
    int pix = y * NW + xb;
    float4 v4 = *(const float4*)(vb + pix);
    float vv[4] = {v4.x, v4.y, v4.z, v4.w};
    float cmap[4];
#pragma unroll
    for (int k = 0; k < 4; k++) {
        float mx = cm[k];
#pragma unroll
        for (int u = 1; u < 7; u++) mx = fmaxf(mx, cm[k+u]);
        bool keep = (mx == vv[k]) && (vv[k] > thr_keep);
        cmap[k] = keep ? vv[k] : 0.0f;
        if (keep) {
            int pos = atomicAdd(&ccnt[b], 1);
            if (pos < CAPC) {
                unsigned u = __float_as_uint(vv[k]);
                unsigned ou = ((int)u < 0) ? ~u : (u | 0x80000000u);
                keys[(size_t)b * CAPC + pos] = ((u64)ou << 19) | (u64)(HWSZ - 1 - (pix + k));
            }
        }
    }
    *(float4*)(cmap_out + b * HWSZ + pix) = make_float4(cmap[0],cmap[1],cmap[2],cmap[3]);
}

// Descending bitonic sort of a[0..np2) in LDS. Keys unique (or 0) -> deterministic.
__device__ inline void bitonic_desc(u64* a, int np2, int tid, int T) {
    for (int k = 2; k <= np2; k <<= 1) {
        for (int j = k >> 1; j > 0; j >>= 1) {
            for (int i = tid; i < np2; i += T) {
                int ixj = i ^ j;
                if (ixj > i) {
                    u64 x = a[i], y = a[ixj];
                    bool up = ((i & k) == 0);
                    if (up ? (x < y) : (x > y)) { a[i] = y; a[ixj] = x; }
                }
            }
            __syncthreads();
        }
    }
}

// ---------------- K4: top-200 via LDS bitonic sort ----------------
__global__ __launch_bounds__(1024) void k_topk(const u64* __restrict__ keys_g,
                                               const int* __restrict__ ccnt,
                                               float* __restrict__ cxArr,
                                               float* __restrict__ cyArr,
                                               float* __restrict__ out_centers,
                                               float* __restrict__ out_topvals) {
    __shared__ u64 sk[CHUNK];
    __shared__ u64 cur[512];
    const int T = 1024;
    int b = blockIdx.x;
    int tid = threadIdx.x;
    int n = ccnt[b];
    if (n > CAPC) n = CAPC;
    const u64* Kg = keys_g + (size_t)b * CAPC;
    int nch = (n + CHUNK - 1) / CHUNK;
    if (nch < 1) nch = 1;
    if (tid < 512) cur[tid] = 0;
    __syncthreads();
    for (int ch = 0; ch < nch; ch++) {
        int off = ch * CHUNK;
        int len = n - off; if (len < 0) len = 0; if (len > CHUNK) len = CHUNK;
        int np2 = 256; while (np2 < len) np2 <<= 1;
        for (int c = tid; c < np2; c += T) sk[c] = (c < len) ? Kg[off + c] : 0;
        __syncthreads();
        bitonic_desc(sk, np2, tid, T);
        if (ch == 0) {
            if (tid < TK) cur[tid] = sk[tid];
            __syncthreads();
        } else {
            if (tid < TK) cur[TK + tid] = sk[tid];
            else if (tid < 512) { if (tid >= 2 * TK) cur[tid] = 0; }
            __syncthreads();
            bitonic_desc(cur, 512, tid, T);
        }
    }
    if (tid < TK) {
        u64 w = cur[tid];
        bool valid = (w != 0ULL);
        unsigned ou = (unsigned)(w >> 19);
        unsigned ub = (ou & 0x80000000u) ? (ou & 0x7FFFFFFFu) : ~ou;
        float v = __uint_as_float(ub);
        int pix = valid ? (int)(HWSZ - 1 - (int)(w & 0x7FFFFULL)) : 0x7fffffff;
        int ys = pix >> 10;
        int xs = pix & (NW - 1);
        cxArr[b * TK + tid] = valid ? (float)xs : 1e9f;
        cyArr[b * TK + tid] = valid ? (float)ys : 1e9f;
        out_centers[(b * TK + tid) * 2 + 0] = (float)ys;
        out_centers[(b * TK + tid) * 2 + 1] = (float)xs;
        out_topvals[b * TK + tid] = valid ? v : -INFINITY;
    }
}

// ---------------- K5: instance assignment + LDS-aggregated seg_counts ----------------
__global__ __launch_bounds__(256) void k_assign(const float* __restrict__ reg,
                                                const int* __restrict__ segid,
                                                const float* __restrict__ cxArr,
                                                const float* __restrict__ cyArr,
                                                float* __restrict__ out_inst,
                                                int* __restrict__ instid,
                                                int* __restrict__ segcnt) {
    __shared__ float scx[TK];
    __shared__ float scy[TK];
    __shared__ int lcnt[TK * NC];
    int tid = threadIdx.x;
    int base = blockIdx.x * ACH;
    int b = base >> 19;
    if (tid < TK) {
        scx[tid] = cxArr[b * TK + tid];
        scy[tid] = cyArr[b * TK + tid];
    }
    for (int t = tid; t < TK * NC; t += 256) lcnt[t] = 0;
    __syncthreads();
    const float* r0 = reg + (size_t)b * 2 * HWSZ;
    const float* r1 = r0 + HWSZ;
    float px[4], py[4], bd[4];
    int bk[4];
#pragma unroll
    for (int it = 0; it < 4; it++) {
        int pix = (base & (HWSZ - 1)) + it * 256 + tid;
        int y = pix >> 10;
        int x = pix & (NW - 1);
        px[it] = __fsub_rn((float)(x + 1), r0[pix]);
        py[it] = __fsub_rn((float)(y + 1), r1[pix]);
        bd[it] = INFINITY; bk[it] = 0;
    }
#pragma unroll 4
    for (int k = 0; k < TK; k++) {
        float cx = scx[k];
        float cy = scy[k];
#pragma unroll
        for (int it = 0; it < 4; it++) {
            float dx = __fsub_rn(px[it], cx);
            float dy = __fsub_rn(py[it], cy);
            float d2 = __fadd_rn(__fmul_rn(dx, dx), __fmul_rn(dy, dy));
            if (d2 < bd[it]) { bd[it] = d2; bk[it] = k; }
        }
    }
#pragma unroll
    for (int it = 0; it < 4; it++) {
        int p = base + it * 256 + tid;
        int cls = segid[p];
        int thing = (cls >= 24) ? 1 : 0;
        int inst = (bk[it] + 1) * thing;
        out_inst[p] = (float)inst;
        instid[p] = inst;
        if (inst) atomicAdd(&lcnt[bk[it] * NC + cls], 1);
    }
    __syncthreads();
    for (int t = tid; t < TK * NC; t += 256) {
        int v = lcnt[t];
        if (v) atomicAdd(&segcnt[b * TK * NC + t], v);
    }
}

// ---------------- K6: per-instance class argmax + size ----------------
__global__ __launch_bounds__(256) void k_stats(const int* __restrict__ segcnt,
                                               float* __restrict__ out_icls,
                                               float* __restrict__ out_isize,
                                               int* __restrict__ icls,
                                               int* __restrict__ isize) {
    int t = blockIdx.x * 256 + threadIdx.x;
    if (t >= NB * TK) return;
    const int* row = segcnt + (size_t)t * NC;
    int total = 0; int bc = 0; int bv = -1;
#pragma unroll
    for (int c = 0; c < NC; c++) {
        int v = row[c];
        total += v;
        if (v > bv) { bv = v; bc = c; }
    }
    out_icls[t] = (float)bc;
    out_isize[t] = (float)total;
    icls[t] = bc;
    isize[t] = total;
}

// ---------------- K7: prob sum of selected class, LDS-aggregated ----------------
__global__ __launch_bounds__(256) void k_probsum(const float* __restrict__ logits,
                                                 const int* __restrict__ instid,
                                                 const float* __restrict__ mArr,
                                                 const float* __restrict__ dArr,
                                                 const int* __restrict__ icls,
                                                 float* __restrict__ probsum) {
    __shared__ float lps[TK];
    int tid = threadIdx.x;
    int base = blockIdx.x * ACH;
    int b = base >> 19;
    for (int t = tid; t < TK; t += 256) lps[t] = 0.f;
    __syncthreads();
#pragma unroll
    for (int it = 0; it < 4; it++) {
        int p = base + it * 256 + tid;
        int inst = instid[p];
        if (inst) {
            int pix = p & (HWSZ - 1);
            int c = icls[b * TK + inst - 1];
            float xv = logits[(size_t)(b * NC + c) * HWSZ + pix];
            float pr = __fdiv_rn(expf(__fsub_rn(xv, mArr[p])), dArr[p]);
            atomicAdd(&lps[inst - 1], pr);
        }
    }
    __syncthreads();
    for (int t = tid; t < TK; t += 256) {
        float s = lps[t];
        if (s != 0.f) atomicAdd(&probsum[b * TK + t], s);
    }
}

// ---------------- K8: finalize inst_seg_prob ----------------
__global__ __launch_bounds__(256) void k_final(const float* __restrict__ probsum,
                                               const int* __restrict__ isize,
                                               float* __restrict__ out_iprob) {
    int t = blockIdx.x * 256 + threadIdx.x;
    if (t >= NB * TK) return;
    float s = probsum[t];
    float sz = (float)isize[t];
    out_iprob[t] = __fdiv_rn(s, fmaxf(sz, 1.0f));
}

// Host: replicate _circle_constants threshold exactly (NumPy pairwise sum, f32)
static float compute_thr_keep() {
    float cdm[121];
    int t = 0;
    for (int i = 0; i < 11; i++) {
        for (int j = 0; j < 11; j++) {
            float ox = (float)(j - 5), oy = (float)(i - 5);
            float cd = sqrtf(ox * ox + oy * oy);
            float cm = (cd <= 5.0f) ? 1.0f : 0.0f;
            cdm[t++] = cd * cm;
        }
    }
    float r[8];
    for (int k = 0; k < 8; k++) r[k] = cdm[k];
    int i = 8;
    for (; i < 121 - (121 % 8); i += 8)
        for (int k = 0; k < 8; k++) r[k] += cdm[i + k];
    float res = ((r[0] + r[1]) + (r[2] + r[3])) + ((r[4] + r[5]) + (r[6] + r[7]));
    for (; i < 121; i++) res += cdm[i];
    float thr = res / 81.0f;
    double kt = -(double)thr - 1.0;
    return (float)kt;
}

extern "C" void kernel_launch(void* const* d_in, const int* in_sizes, int n_in,
                              void* d_out, int out_size, void* d_ws, size_t ws_size,
                              hipStream_t stream) {
    const float* logits = (const float*)d_in[0];
    const float* reg    = (const float*)d_in[2];
    float* out = (float*)d_out;

    // output layout (all f32)
    float* o_inst    = out;                       // B*HW
    float* o_seg     = out + 1048576;             // B*HW
    float* o_centers = out + 2097152;             // B*TK*2
    float* o_topvals = out + 2097952;             // B*TK
    float* o_icls    = out + 2098352;             // B*TK
    float* o_iprob   = out + 2098752;             // B*TK
    float* o_isize   = out + 2099152;             // B*TK
    float* o_cmap    = out + 2099552;             // B*HW

    // workspace: keys (8B aligned) first, then contiguous zero-region, then rest
    u64* keys = (u64*)d_ws;                                   // NB*CAPC
    float* wsf = (float*)(keys + (size_t)NB * CAPC);
    size_t o = 0;
    int*   zreg   = (int*)(wsf + o); o += ZWORDS;             // [ccnt(8) | segcnt | probsum]
    int*   ccnt   = zreg;
    int*   segcnt = zreg + 8;
    float* probsum= (float*)(zreg + 8 + NB * TK * NC);
    float* vote   = wsf + o; o += (size_t)NB * HWSZ;
    float* mArr   = wsf + o; o += (size_t)NB * HWSZ;
    float* dArr   = wsf + o; o += (size_t)NB * HWSZ;
    int*   segid  = (int*)(wsf + o); o += (size_t)NB * HWSZ;
    int*   instid = (int*)(wsf + o); o += (size_t)NB * HWSZ;
    float* cxArr  = wsf + o; o += NB * TK;
    float* cyArr  = wsf + o; o += NB * TK;
    int*   icls   = (int*)(wsf + o); o += NB * TK;
    int*   isize  = (int*)(wsf + o); o += NB * TK;

    float thr_keep = compute_thr_keep();

    int gridPix = (NB * HWSZ) / 256;   // 4096
    int gridRow = NB * NH;             // 1024: one image row per block, 4 px/thread
    int gridAgg = (NB * HWSZ) / ACH;   // 1024

    k_seg<<<gridPix, 256, 0, stream>>>(logits, o_seg, segid, mArr, dArr, zreg);
    k_vote<<<gridRow, 256, 0, stream>>>(reg, vote);
    k_pool<<<gridRow, 256, 0, stream>>>(vote, o_cmap, keys, ccnt, thr_keep);
    k_topk<<<NB, 1024, 0, stream>>>(keys, ccnt, cxArr, cyArr, o_centers, o_topvals);
    k_assign<<<gridAgg, 256, 0, stream>>>(reg, segid, cxArr, cyArr, o_inst, instid, segcnt);
    k_stats<<<(NB * TK + 255) / 256, 256, 0, stream>>>(segcnt, o_icls, o_isize, icls, isize);
    k_probsum<<<gridAgg, 256, 0, stream>>>(logits, instid, mArr, dArr, icls, probsum);
    k_final<<<(NB * TK + 255) / 256, 256, 0, stream>>>(probsum, isize, o_iprob);
}

// Round 8
// 470.691 us; speedup vs baseline: 1.3080x; 1.0446x over previous
//
#include <hip/hip_runtime.h>
#include <cfloat>
#include <cmath>

#define NB 2
#define NC 34
#define NH 512
#define NW 1024
#define HWSZ (NH*NW)          // 524288 = 2^19
#define TK 200
#define CAPC 49152            // >= plausible 7x7 local-maxima count
#define CHUNK 8192            // LDS sort chunk (64KB)
#define ACH 1024              // pixels per block for aggregation kernels
#define ZWORDS (8 + NB*TK*NC + NB*TK)   // ccnt + segcnt + probsum, contiguous

typedef unsigned long long u64;

// ---------------- K1: softmax argmax + max + denom (two-pass exact) + zero-fold ----------------
__global__ __launch_bounds__(256) void k_seg(const float* __restrict__ logits,
                                             float* __restrict__ segmap_out,
                                             int* __restrict__ segid,
                                             float* __restrict__ mArr,
                                             float* __restrict__ dArr,
                                             int* __restrict__ zreg) {
    int p = blockIdx.x * 256 + threadIdx.x;
    if (p < ZWORDS) zreg[p] = 0;          // zero ccnt/segcnt/probsum (first 55 blocks)
    if (p >= NB * HWSZ) return;
    int b = p >> 19;
    int pix = p & (HWSZ - 1);
    const float* base = logits + (size_t)b * NC * HWSZ + pix;
    float v[NC];
#pragma unroll
    for (int c = 0; c < NC; c++) v[c] = base[(size_t)c * HWSZ];
    float m = -FLT_MAX; int bc = 0;
#pragma unroll
    for (int c = 0; c < NC; c++) { if (v[c] > m) { m = v[c]; bc = c; } }
    float den = 0.f;
#pragma unroll
    for (int c = 0; c < NC; c++) den += expf(v[c] - m);
    segmap_out[p] = (float)bc;
    segid[p] = bc;
    mArr[p] = m;
    dArr[p] = den;
}

// ---------------- K2: vote map, 4 px/thread, vectorized + software-pipelined ----------------
// Interior lanes load the 14-wide window as 2 scalars + 3 aligned float4 per
// array (10 load insts/row vs 28 guarded scalars); ping-pong windows overlap
// row i+1's loads with row i's math. Exact f32 term order preserved: i asc,
// j asc within i, identical __f*_rn ops. Edge lanes (tid 0,1,254,255) keep
// the guarded-scalar path (zero-pad per reference).
__global__ __launch_bounds__(256, 4) void k_vote(const float* __restrict__ reg,
                                                 float* __restrict__ vote) {
    int tid = threadIdx.x;
    int blk = blockIdx.x;
    int b = blk >> 9;
    int y = blk & 511;
    int xb = tid << 2;                    // pixels x = xb..xb+3
    const float* r0 = reg + (size_t)b * 2 * HWSZ;
    const float* r1 = r0 + HWSZ;
    const bool interior = (tid >= 2) && (tid <= 253);   // window [xb-5, xb+8] fully in-row
    float a0 = 0.f, a1 = 0.f, a2 = 0.f, a3 = 0.f;

    float sA0[14], sA1[14], sB0[14], sB1[14];

    auto loadwin = [&](int i, float* s0, float* s1) {
        int d = i - 5;
        int yy = y + d;
        bool rowin = (yy >= 0) && (yy < NH);
        if (!rowin) {
#pragma unroll
            for (int t = 0; t < 14; t++) { s0[t] = 0.f; s1[t] = 0.f; }
            return;
        }
        const float* p0 = r0 + (size_t)yy * NW;
        const float* p1 = r1 + (size_t)yy * NW;
        if (interior) {
            float la = p0[xb - 5];
            float4 B = *(const float4*)(p0 + xb - 4);
            float4 C = *(const float4*)(p0 + xb);
            float4 D = *(const float4*)(p0 + xb + 4);
            float le = p0[xb + 8];
            s0[0]=la; s0[1]=B.x; s0[2]=B.y; s0[3]=B.z; s0[4]=B.w;
            s0[5]=C.x; s0[6]=C.y; s0[7]=C.z; s0[8]=C.w;
            s0[9]=D.x; s0[10]=D.y; s0[11]=D.z; s0[12]=D.w; s0[13]=le;
            la = p1[xb - 5];
            B = *(const float4*)(p1 + xb - 4);
            C = *(const float4*)(p1 + xb);
            D = *(const float4*)(p1 + xb + 4);
            le = p1[xb + 8];
            s1[0]=la; s1[1]=B.x; s1[2]=B.y; s1[3]=B.z; s1[4]=B.w;
            s1[5]=C.x; s1[6]=C.y; s1[7]=C.z; s1[8]=C.w;
            s1[9]=D.x; s1[10]=D.y; s1[11]=D.z; s1[12]=D.w; s1[13]=le;
        } else {
#pragma unroll
            for (int t = 0; t < 14; t++) {
                int xx = xb - 5 + t;
                bool in = (xx >= 0) && (xx < NW);
                s0[t] = in ? p0[xx] : 0.f;
                s1[t] = in ? p1[xx] : 0.f;
            }
        }
    };

    auto compute = [&](int i, const float* s0, const float* s1) {
        int d = i - 5;
        int ad = d < 0 ? -d : d;
        int w = (int)sqrtf((float)(25 - ad * ad));   // exact for {0,9,16,21,24,25}
        int lo = 5 - w, hi = 5 + w;                  // circle-mask j-range, wave-uniform
        float di = (float)d;
#pragma unroll
        for (int j = 0; j < 11; j++) {
            if (j < lo || j > hi) continue;          // uniform scalar branch
            float dj = (float)(j - 5);
            float dx, dy, ss;
            dx = __fsub_rn(dj, s0[j+0]); dy = __fsub_rn(di, s1[j+0]);
            ss = __fadd_rn(__fmul_rn(dx,dx), __fmul_rn(dy,dy));
            a0 = __fadd_rn(a0, sqrtf(ss));
            dx = __fsub_rn(dj, s0[j+1]); dy = __fsub_rn(di, s1[j+1]);
            ss = __fadd_rn(__fmul_rn(dx,dx), __fmul_rn(dy,dy));
            a1 = __fadd_rn(a1, sqrtf(ss));
            dx = __fsub_rn(dj, s0[j+2]); dy = __fsub_rn(di, s1[j+2]);
            ss = __fadd_rn(__fmul_rn(dx,dx), __fmul_rn(dy,dy));
            a2 = __fadd_rn(a2, sqrtf(ss));
            dx = __fsub_rn(dj, s0[j+3]); dy = __fsub_rn(di, s1[j+3]);
            ss = __fadd_rn(__fmul_rn(dx,dx), __fmul_rn(dy,dy));
            a3 = __fadd_rn(a3, sqrtf(ss));
        }
    };

    loadwin(0, sA0, sA1);
#pragma unroll 1
    for (int i = 0; i < 10; i += 2) {     // i = 0,2,4,6,8
        loadwin(i + 1, sB0, sB1);         // prefetch next row
        compute(i, sA0, sA1);
        loadwin(i + 2, sA0, sA1);         // prefetch row after (i+2 <= 10)
        compute(i + 1, sB0, sB1);
    }
    compute(10, sA0, sA1);                // rows computed in order 0..10

    float4 vv;
    vv.x = __fsub_rn(-__fdiv_rn(a0, 81.0f), 1.0f);
    vv.y = __fsub_rn(-__fdiv_rn(a1, 81.0f), 1.0f);
    vv.z = __fsub_rn(-__fdiv_rn(a2, 81.0f), 1.0f);
    vv.w = __fsub_rn(-__fdiv_rn(a3, 81.0f), 1.0f);
    *(float4*)(vote + b * HWSZ + y * NW + xb) = vv;
}

// ---------------- K3: 7x7 max pool via column maxes, keep, key compaction ----------------
__global__ __launch_bounds__(256) void k_pool(const float* __restrict__ vote,
                                              float* __restrict__ cmap_out,
                                              u64* __restrict__ keys,
                                              int* __restrict__ ccnt,
                                              float thr_keep) {
    int tid = threadIdx.x;
    int blk = blockIdx.x;
    int b = blk >> 9;
    int y = blk & 511;
    int xb = tid << 2;
    const float* vb = vote + (size_t)b * HWSZ;
    float cm[10];
#pragma unroll
    for (int t = 0; t < 10; t++) cm[t] = -INFINITY;
#pragma unroll 1
    for (int dy = -3; dy <= 3; dy++) {
        int yy = y + dy;
        if (yy < 0 || yy >= NH) continue;
        const float* row = vb + (size_t)yy * NW;
#pragma unroll
        for (int t = 0; t < 10; t++) {
            int xx = xb - 3 + t;
            if (xx >= 0 && xx < NW) cm[t] = fmaxf(cm[t], row[xx]);
        }
    }
    int pix = y * NW + xb;
    float4 v4 = *(const float4*)(vb + pix);
    float vv[4] = {v4.x, v4.y, v4.z, v4.w};
    float cmap[4];
#pragma unroll
    for (int k = 0; k < 4; k++) {
        float mx = cm[k];
#pragma unroll
        for (int u = 1; u < 7; u++) mx = fmaxf(mx, cm[k+u]);
        bool keep = (mx == vv[k]) && (vv[k] > thr_keep);
        cmap[k] = keep ? vv[k] : 0.0f;
        if (keep) {
            int pos = atomicAdd(&ccnt[b], 1);
            if (pos < CAPC) {
                unsigned u = __float_as_uint(vv[k]);
                unsigned ou = ((int)u < 0) ? ~u : (u | 0x80000000u);
                keys[(size_t)b * CAPC + pos] = ((u64)ou << 19) | (u64)(HWSZ - 1 - (pix + k));
            }
        }
    }
    *(float4*)(cmap_out + b * HWSZ + pix) = make_float4(cmap[0],cmap[1],cmap[2],cmap[3]);
}

// Descending bitonic sort of a[0..np2) in LDS. Keys unique (or 0) -> deterministic.
__device__ inline void bitonic_desc(u64* a, int np2, int tid, int T) {
    for (int k = 2; k <= np2; k <<= 1) {
        for (int j = k >> 1; j > 0; j >>= 1) {
            for (int i = tid; i < np2; i += T) {
                int ixj = i ^ j;
                if (ixj > i) {
                    u64 x = a[i], y = a[ixj];
                    bool up = ((i & k) == 0);
                    if (up ? (x < y) : (x > y)) { a[i] = y; a[ixj] = x; }
                }
            }
            __syncthreads();
        }
    }
}

// ---------------- K4: top-200 via LDS bitonic sort ----------------
__global__ __launch_bounds__(1024) void k_topk(const u64* __restrict__ keys_g,
                                               const int* __restrict__ ccnt,
                                               float* __restrict__ cxArr,
                                               float* __restrict__ cyArr,
                                               float* __restrict__ out_centers,
                                               float* __restrict__ out_topvals) {
    __shared__ u64 sk[CHUNK];
    __shared__ u64 cur[512];
    const int T = 1024;
    int b = blockIdx.x;
    int tid = threadIdx.x;
    int n = ccnt[b];
    if (n > CAPC) n = CAPC;
    const u64* Kg = keys_g + (size_t)b * CAPC;
    int nch = (n + CHUNK - 1) / CHUNK;
    if (nch < 1) nch = 1;
    if (tid < 512) cur[tid] = 0;
    __syncthreads();
    for (int ch = 0; ch < nch; ch++) {
        int off = ch * CHUNK;
        int len = n - off; if (len < 0) len = 0; if (len > CHUNK) len = CHUNK;
        int np2 = 256; while (np2 < len) np2 <<= 1;
        for (int c = tid; c < np2; c += T) sk[c] = (c < len) ? Kg[off + c] : 0;
        __syncthreads();
        bitonic_desc(sk, np2, tid, T);
        if (ch == 0) {
            if (tid < TK) cur[tid] = sk[tid];
            __syncthreads();
        } else {
            if (tid < TK) cur[TK + tid] = sk[tid];
            else if (tid < 512) { if (tid >= 2 * TK) cur[tid] = 0; }
            __syncthreads();
            bitonic_desc(cur, 512, tid, T);
        }
    }
    if (tid < TK) {
        u64 w = cur[tid];
        bool valid = (w != 0ULL);
        unsigned ou = (unsigned)(w >> 19);
        unsigned ub = (ou & 0x80000000u) ? (ou & 0x7FFFFFFFu) : ~ou;
        float v = __uint_as_float(ub);
        int pix = valid ? (int)(HWSZ - 1 - (int)(w & 0x7FFFFULL)) : 0x7fffffff;
        int ys = pix >> 10;
        int xs = pix & (NW - 1);
        cxArr[b * TK + tid] = valid ? (float)xs : 1e9f;
        cyArr[b * TK + tid] = valid ? (float)ys : 1e9f;
        out_centers[(b * TK + tid) * 2 + 0] = (float)ys;
        out_centers[(b * TK + tid) * 2 + 1] = (float)xs;
        out_topvals[b * TK + tid] = valid ? v : -INFINITY;
    }
}

// ---------------- K5: instance assignment + LDS-aggregated seg_counts ----------------
__global__ __launch_bounds__(256) void k_assign(const float* __restrict__ reg,
                                                const int* __restrict__ segid,
                                                const float* __restrict__ cxArr,
                                                const float* __restrict__ cyArr,
                                                float* __restrict__ out_inst,
                                                int* __restrict__ instid,
                                                int* __restrict__ segcnt) {
    __shared__ float scx[TK];
    __shared__ float scy[TK];
    __shared__ int lcnt[TK * NC];
    int tid = threadIdx.x;
    int base = blockIdx.x * ACH;
    int b = base >> 19;
    if (tid < TK) {
        scx[tid] = cxArr[b * TK + tid];
        scy[tid] = cyArr[b * TK + tid];
    }
    for (int t = tid; t < TK * NC; t += 256) lcnt[t] = 0;
    __syncthreads();
    const float* r0 = reg + (size_t)b * 2 * HWSZ;
    const float* r1 = r0 + HWSZ;
    float px[4], py[4], bd[4];
    int bk[4];
#pragma unroll
    for (int it = 0; it < 4; it++) {
        int pix = (base & (HWSZ - 1)) + it * 256 + tid;
        int y = pix >> 10;
        int x = pix & (NW - 1);
        px[it] = __fsub_rn((float)(x + 1), r0[pix]);
        py[it] = __fsub_rn((float)(y + 1), r1[pix]);
        bd[it] = INFINITY; bk[it] = 0;
    }
#pragma unroll 4
    for (int k = 0; k < TK; k++) {
        float cx = scx[k];
        float cy = scy[k];
#pragma unroll
        for (int it = 0; it < 4; it++) {
            float dx = __fsub_rn(px[it], cx);
            float dy = __fsub_rn(py[it], cy);
            float d2 = __fadd_rn(__fmul_rn(dx, dx), __fmul_rn(dy, dy));
            if (d2 < bd[it]) { bd[it] = d2; bk[it] = k; }
        }
    }
#pragma unroll
    for (int it = 0; it < 4; it++) {
        int p = base + it * 256 + tid;
        int cls = segid[p];
        int thing = (cls >= 24) ? 1 : 0;
        int inst = (bk[it] + 1) * thing;
        out_inst[p] = (float)inst;
        instid[p] = inst;
        if (inst) atomicAdd(&lcnt[bk[it] * NC + cls], 1);
    }
    __syncthreads();
    for (int t = tid; t < TK * NC; t += 256) {
        int v = lcnt[t];
        if (v) atomicAdd(&segcnt[b * TK * NC + t], v);
    }
}

// ---------------- K6: per-instance class argmax + size ----------------
__global__ __launch_bounds__(256) void k_stats(const int* __restrict__ segcnt,
                                               float* __restrict__ out_icls,
                                               float* __restrict__ out_isize,
                                               int* __restrict__ icls,
                                               int* __restrict__ isize) {
    int t = blockIdx.x * 256 + threadIdx.x;
    if (t >= NB * TK) return;
    const int* row = segcnt + (size_t)t * NC;
    int total = 0; int bc = 0; int bv = -1;
#pragma unroll
    for (int c = 0; c < NC; c++) {
        int v = row[c];
        total += v;
        if (v > bv) { bv = v; bc = c; }
    }
    out_icls[t] = (float)bc;
    out_isize[t] = (float)total;
    icls[t] = bc;
    isize[t] = total;
}

// ---------------- K7: prob sum of selected class, LDS-aggregated ----------------
__global__ __launch_bounds__(256) void k_probsum(const float* __restrict__ logits,
                                                 const int* __restrict__ instid,
                                                 const float* __restrict__ mArr,
                                                 const float* __restrict__ dArr,
                                                 const int* __restrict__ icls,
                                                 float* __restrict__ probsum) {
    __shared__ float lps[TK];
    int tid = threadIdx.x;
    int base = blockIdx.x * ACH;
    int b = base >> 19;
    for (int t = tid; t < TK; t += 256) lps[t] = 0.f;
    __syncthreads();
#pragma unroll
    for (int it = 0; it < 4; it++) {
        int p = base + it * 256 + tid;
        int inst = instid[p];
        if (inst) {
            int pix = p & (HWSZ - 1);
            int c = icls[b * TK + inst - 1];
            float xv = logits[(size_t)(b * NC + c) * HWSZ + pix];
            float pr = __fdiv_rn(expf(__fsub_rn(xv, mArr[p])), dArr[p]);
            atomicAdd(&lps[inst - 1], pr);
        }
    }
    __syncthreads();
    for (int t = tid; t < TK; t += 256) {
        float s = lps[t];
        if (s != 0.f) atomicAdd(&probsum[b * TK + t], s);
    }
}

// ---------------- K8: finalize inst_seg_prob ----------------
__global__ __launch_bounds__(256) void k_final(const float* __restrict__ probsum,
                                               const int* __restrict__ isize,
                                               float* __restrict__ out_iprob) {
    int t = blockIdx.x * 256 + threadIdx.x;
    if (t >= NB * TK) return;
    float s = probsum[t];
    float sz = (float)isize[t];
    out_iprob[t] = __fdiv_rn(s, fmaxf(sz, 1.0f));
}

// Host: replicate _circle_constants threshold exactly (NumPy pairwise sum, f32)
static float compute_thr_keep() {
    float cdm[121];
    int t = 0;
    for (int i = 0; i < 11; i++) {
        for (int j = 0; j < 11; j++) {
            float ox = (float)(j - 5), oy = (float)(i - 5);
            float cd = sqrtf(ox * ox + oy * oy);
            float cm = (cd <= 5.0f) ? 1.0f : 0.0f;
            cdm[t++] = cd * cm;
        }
    }
    float r[8];
    for (int k = 0; k < 8; k++) r[k] = cdm[k];
    int i = 8;
    for (; i < 121 - (121 % 8); i += 8)
        for (int k = 0; k < 8; k++) r[k] += cdm[i + k];
    float res = ((r[0] + r[1]) + (r[2] + r[3])) + ((r[4] + r[5]) + (r[6] + r[7]));
    for (; i < 121; i++) res += cdm[i];
    float thr = res / 81.0f;
    double kt = -(double)thr - 1.0;
    return (float)kt;
}

extern "C" void kernel_launch(void* const* d_in, const int* in_sizes, int n_in,
                              void* d_out, int out_size, void* d_ws, size_t ws_size,
                              hipStream_t stream) {
    const float* logits = (const float*)d_in[0];
    const float* reg    = (const float*)d_in[2];
    float* out = (float*)d_out;

    // output layout (all f32)
    float* o_inst    = out;                       // B*HW
    float* o_seg     = out + 1048576;             // B*HW
    float* o_centers = out + 2097152;             // B*TK*2
    float* o_topvals = out + 2097952;             // B*TK
    float* o_icls    = out + 2098352;             // B*TK
    float* o_iprob   = out + 2098752;             // B*TK
    float* o_isize   = out + 2099152;             // B*TK
    float* o_cmap    = out + 2099552;             // B*HW

    // workspace: keys (8B aligned) first, then contiguous zero-region, then rest
    u64* keys = (u64*)d_ws;                                   // NB*CAPC
    float* wsf = (float*)(keys + (size_t)NB * CAPC);
    size_t o = 0;
    int*   zreg   = (int*)(wsf + o); o += ZWORDS;             // [ccnt(8) | segcnt | probsum]
    int*   ccnt   = zreg;
    int*   segcnt = zreg + 8;
    float* probsum= (float*)(zreg + 8 + NB * TK * NC);
    float* vote   = wsf + o; o += (size_t)NB * HWSZ;
    float* mArr   = wsf + o; o += (size_t)NB * HWSZ;
    float* dArr   = wsf + o; o += (size_t)NB * HWSZ;
    int*   segid  = (int*)(wsf + o); o += (size_t)NB * HWSZ;
    int*   instid = (int*)(wsf + o); o += (size_t)NB * HWSZ;
    float* cxArr  = wsf + o; o += NB * TK;
    float* cyArr  = wsf + o; o += NB * TK;
    int*   icls   = (int*)(wsf + o); o += NB * TK;
    int*   isize  = (int*)(wsf + o); o += NB * TK;

    float thr_keep = compute_thr_keep();

    int gridPix = (NB * HWSZ) / 256;   // 4096
    int gridRow = NB * NH;             // 1024: one image row per block, 4 px/thread
    int gridAgg = (NB * HWSZ) / ACH;   // 1024

    k_seg<<<gridPix, 256, 0, stream>>>(logits, o_seg, segid, mArr, dArr, zreg);
    k_vote<<<gridRow, 256, 0, stream>>>(reg, vote);
    k_pool<<<gridRow, 256, 0, stream>>>(vote, o_cmap, keys, ccnt, thr_keep);
    k_topk<<<NB, 1024, 0, stream>>>(keys, ccnt, cxArr, cyArr, o_centers, o_topvals);
    k_assign<<<gridAgg, 256, 0, stream>>>(reg, segid, cxArr, cyArr, o_inst, instid, segcnt);
    k_stats<<<(NB * TK + 255) / 256, 256, 0, stream>>>(segcnt, o_icls, o_isize, icls, isize);
    k_probsum<<<gridAgg, 256, 0, stream>>>(logits, instid, mArr, dArr, icls, probsum);
    k_final<<<(NB * TK + 255) / 256, 256, 0, stream>>>(probsum, isize, o_iprob);
}

// Round 9
// 458.721 us; speedup vs baseline: 1.3422x; 1.0261x over previous
//
#include <hip/hip_runtime.h>
#include <cfloat>
#include <cmath>

#define NB 2
#define NC 34
#define NH 512
#define NW 1024
#define HWSZ (NH*NW)          // 524288 = 2^19
#define TK 200
#define CAPC 49152            // >= plausible 7x7 local-maxima count
#define CHUNK 8192            // LDS sort chunk (64KB)
#define ACH 1024              // pixels per block for aggregation kernels
#define ZWORDS (8 + NB*TK*NC + NB*TK)   // ccnt + segcnt + probsum, contiguous

// padded layouts
#define PST 1040              // padded row stride (16 | 1040 -> float4 alignment holds)
#define RPROWS 522            // reg pad: 5 top + 512 + 5 bottom
#define RPLEFT 8              // reg pad: left 8 (covers window start xb-8), right 8
#define VPROWS 518            // vote pad: 3 top + 512 + 3 bottom
#define VPLEFT 4              // vote pad: left 4, right 12
#define RPSZ (RPROWS*PST)     // per batch-channel
#define VPSZ (VPROWS*PST)     // per batch

typedef unsigned long long u64;

// ---------------- K0: build zero-padded reg + (-inf)-filled vote pad ----------------
__global__ __launch_bounds__(256) void k_prep(const float* __restrict__ reg,
                                              float* __restrict__ reg_pad,
                                              float* __restrict__ vote_pad) {
    int t = blockIdx.x * 256 + threadIdx.x;
    if (t < NB * VPSZ) vote_pad[t] = -INFINITY;          // k_vote overwrites interior
    if (t < NB * 2 * RPSZ) {
        int c = t % PST;
        int rest = t / PST;
        int r = rest % RPROWS;
        int bc = rest / RPROWS;            // b*2 + ch
        int rr = r - 5, cc = c - RPLEFT;
        float v = 0.f;
        if (rr >= 0 && rr < NH && cc >= 0 && cc < NW)
            v = reg[(size_t)bc * HWSZ + rr * NW + cc];
        reg_pad[t] = v;
    }
}

// ---------------- K1: softmax argmax + max + denom (two-pass exact) + zero-fold ----------------
__global__ __launch_bounds__(256) void k_seg(const float* __restrict__ logits,
                                             float* __restrict__ segmap_out,
                                             int* __restrict__ segid,
                                             float* __restrict__ mArr,
                                             float* __restrict__ dArr,
                                             int* __restrict__ zreg) {
    int p = blockIdx.x * 256 + threadIdx.x;
    if (p < ZWORDS) zreg[p] = 0;          // zero ccnt/segcnt/probsum
    if (p >= NB * HWSZ) return;
    int b = p >> 19;
    int pix = p & (HWSZ - 1);
    const float* base = logits + (size_t)b * NC * HWSZ + pix;
    float v[NC];
#pragma unroll
    for (int c = 0; c < NC; c++) v[c] = base[(size_t)c * HWSZ];
    float m = -FLT_MAX; int bc = 0;
#pragma unroll
    for (int c = 0; c < NC; c++) { if (v[c] > m) { m = v[c]; bc = c; } }
    float den = 0.f;
#pragma unroll
    for (int c = 0; c < NC; c++) den += expf(v[c] - m);
    segmap_out[p] = (float)bc;
    segid[p] = bc;
    mArr[p] = m;
    dArr[p] = den;
}

#define GETC(f, idx) (((idx)&3)==0 ? f[(idx)>>2].x : ((idx)&3)==1 ? f[(idx)>>2].y : \
                      ((idx)&3)==2 ? f[(idx)>>2].z : f[(idx)>>2].w)

// ---------------- K2: vote map on padded reg — branch-free aligned loads, pipelined ----------------
// Window for 4 px = real cols [xb-5, xb+8] = padded [xb+3, xb+16] inside the
// aligned 5xfloat4 load starting at padded col xb (real xb-8). Exact f32 term
// order preserved (i asc, j asc, identical __f*_rn ops; pad zeros = reference).
__global__ __launch_bounds__(256, 4) void k_vote(const float* __restrict__ reg_pad,
                                                 float* __restrict__ vote_pad) {
    int tid = threadIdx.x;
    int blk = blockIdx.x;
    int b = blk >> 9;
    int y = blk & 511;
    int xb = tid << 2;
    const float* rp0 = reg_pad + (size_t)(b * 2 + 0) * RPSZ;
    const float* rp1 = reg_pad + (size_t)(b * 2 + 1) * RPSZ;
    float a0 = 0.f, a1 = 0.f, a2 = 0.f, a3 = 0.f;

    float4 fA0[5], fA1[5], fB0[5], fB1[5];

    auto loadwin = [&](int i, float4* f0, float4* f1) {
        const float* p0 = rp0 + (size_t)(y + i) * PST + xb;   // padded row y+i
        const float* p1 = rp1 + (size_t)(y + i) * PST + xb;
#pragma unroll
        for (int t = 0; t < 5; t++) f0[t] = *(const float4*)(p0 + 4 * t);
#pragma unroll
        for (int t = 0; t < 5; t++) f1[t] = *(const float4*)(p1 + 4 * t);
    };

    auto compute = [&](int i, const float4* f0, const float4* f1) {
        int d = i - 5;
        int ad = d < 0 ? -d : d;
        int w = (int)sqrtf((float)(25 - ad * ad));   // exact for {0,9,16,21,24,25}
        int lo = 5 - w, hi = 5 + w;                  // circle-mask j-range (wave-uniform)
        float di = (float)d;
#pragma unroll
        for (int j = 0; j < 11; j++) {
            if (j < lo || j > hi) continue;
            float dj = (float)(j - 5);
            float dx, dy, ss;
            dx = __fsub_rn(dj, GETC(f0, j+3)); dy = __fsub_rn(di, GETC(f1, j+3));
            ss = __fadd_rn(__fmul_rn(dx,dx), __fmul_rn(dy,dy));
            a0 = __fadd_rn(a0, sqrtf(ss));
            dx = __fsub_rn(dj, GETC(f0, j+4)); dy = __fsub_rn(di, GETC(f1, j+4));
            ss = __fadd_rn(__fmul_rn(dx,dx), __fmul_rn(dy,dy));
            a1 = __fadd_rn(a1, sqrtf(ss));
            dx = __fsub_rn(dj, GETC(f0, j+5)); dy = __fsub_rn(di, GETC(f1, j+5));
            ss = __fadd_rn(__fmul_rn(dx,dx), __fmul_rn(dy,dy));
            a2 = __fadd_rn(a2, sqrtf(ss));
            dx = __fsub_rn(dj, GETC(f0, j+6)); dy = __fsub_rn(di, GETC(f1, j+6));
            ss = __fadd_rn(__fmul_rn(dx,dx), __fmul_rn(dy,dy));
            a3 = __fadd_rn(a3, sqrtf(ss));
        }
    };

    loadwin(0, fA0, fA1);
#pragma unroll 1
    for (int i = 0; i < 10; i += 2) {
        loadwin(i + 1, fB0, fB1);
        compute(i, fA0, fA1);
        loadwin(i + 2, fA0, fA1);
        compute(i + 1, fB0, fB1);
    }
    compute(10, fA0, fA1);

    float4 vv;
    vv.x = __fsub_rn(-__fdiv_rn(a0, 81.0f), 1.0f);
    vv.y = __fsub_rn(-__fdiv_rn(a1, 81.0f), 1.0f);
    vv.z = __fsub_rn(-__fdiv_rn(a2, 81.0f), 1.0f);
    vv.w = __fsub_rn(-__fdiv_rn(a3, 81.0f), 1.0f);
    *(float4*)(vote_pad + (size_t)b * VPSZ + (size_t)(y + 3) * PST + (xb + VPLEFT)) = vv;
}

// ---------------- K3: 7x7 max pool on (-inf)-padded vote — branch-free ----------------
__global__ __launch_bounds__(256) void k_pool(const float* __restrict__ vote_pad,
                                              float* __restrict__ cmap_out,
                                              u64* __restrict__ keys,
                                              int* __restrict__ ccnt,
                                              float thr_keep) {
    int tid = threadIdx.x;
    int blk = blockIdx.x;
    int b = blk >> 9;
    int y = blk & 511;
    int xb = tid << 2;
    const float* vp = vote_pad + (size_t)b * VPSZ;
    float cm[10];
#pragma unroll
    for (int t = 0; t < 10; t++) cm[t] = -INFINITY;
    float vv[4];
#pragma unroll 1
    for (int dy = -3; dy <= 3; dy++) {
        const float* row = vp + (size_t)(y + dy + 3) * PST + xb;   // real cols [xb-4, xb+8)
        float4 A = *(const float4*)(row);
        float4 Bq = *(const float4*)(row + 4);
        float4 Cq = *(const float4*)(row + 8);
        float L[12] = {A.x,A.y,A.z,A.w, Bq.x,Bq.y,Bq.z,Bq.w, Cq.x,Cq.y,Cq.z,Cq.w};
#pragma unroll
        for (int t = 0; t < 10; t++) cm[t] = fmaxf(cm[t], L[t + 1]);
        if (dy == 0) { vv[0]=L[4]; vv[1]=L[5]; vv[2]=L[6]; vv[3]=L[7]; }
    }
    int pix = y * NW + xb;
    float cmap[4];
#pragma unroll
    for (int k = 0; k < 4; k++) {
        float mx = cm[k];
#pragma unroll
        for (int u = 1; u < 7; u++) mx = fmaxf(mx, cm[k+u]);
        bool keep = (mx == vv[k]) && (vv[k] > thr_keep);
        cmap[k] = keep ? vv[k] : 0.0f;
        if (keep) {
            int pos = atomicAdd(&ccnt[b], 1);
            if (pos < CAPC) {
                unsigned u = __float_as_uint(vv[k]);
                unsigned ou = ((int)u < 0) ? ~u : (u | 0x80000000u);
                keys[(size_t)b * CAPC + pos] = ((u64)ou << 19) | (u64)(HWSZ - 1 - (pix + k));
            }
        }
    }
    *(float4*)(cmap_out + b * HWSZ + pix) = make_float4(cmap[0],cmap[1],cmap[2],cmap[3]);
}

// Descending bitonic sort of a[0..np2) in LDS. Keys unique (or 0) -> deterministic.
__device__ inline void bitonic_desc(u64* a, int np2, int tid, int T) {
    for (int k = 2; k <= np2; k <<= 1) {
        for (int j = k >> 1; j > 0; j >>= 1) {
            for (int i = tid; i < np2; i += T) {
                int ixj = i ^ j;
                if (ixj > i) {
                    u64 x = a[i], y = a[ixj];
                    bool up = ((i & k) == 0);
                    if (up ? (x < y) : (x > y)) { a[i] = y; a[ixj] = x; }
                }
            }
            __syncthreads();
        }
    }
}

// ---------------- K4: top-200 via LDS bitonic sort ----------------
__global__ __launch_bounds__(1024) void k_topk(const u64* __restrict__ keys_g,
                                               const int* __restrict__ ccnt,
                                               float* __restrict__ cxArr,
                                               float* __restrict__ cyArr,
                                               float* __restrict__ out_centers,
                                               float* __restrict__ out_topvals) {
    __shared__ u64 sk[CHUNK];
    __shared__ u64 cur[512];
    const int T = 1024;
    int b = blockIdx.x;
    int tid = threadIdx.x;
    int n = ccnt[b];
    if (n > CAPC) n = CAPC;
    const u64* Kg = keys_g + (size_t)b * CAPC;
    int nch = (n + CHUNK - 1) / CHUNK;
    if (nch < 1) nch = 1;
    if (tid < 512) cur[tid] = 0;
    __syncthreads();
    for (int ch = 0; ch < nch; ch++) {
        int off = ch * CHUNK;
        int len = n - off; if (len < 0) len = 0; if (len > CHUNK) len = CHUNK;
        int np2 = 256; while (np2 < len) np2 <<= 1;
        for (int c = tid; c < np2; c += T) sk[c] = (c < len) ? Kg[off + c] : 0;
        __syncthreads();
        bitonic_desc(sk, np2, tid, T);
        if (ch == 0) {
            if (tid < TK) cur[tid] = sk[tid];
            __syncthreads();
        } else {
            if (tid < TK) cur[TK + tid] = sk[tid];
            else if (tid < 512) { if (tid >= 2 * TK) cur[tid] = 0; }
            __syncthreads();
            bitonic_desc(cur, 512, tid, T);
        }
    }
    if (tid < TK) {
        u64 w = cur[tid];
        bool valid = (w != 0ULL);
        unsigned ou = (unsigned)(w >> 19);
        unsigned ub = (ou & 0x80000000u) ? (ou & 0x7FFFFFFFu) : ~ou;
        float v = __uint_as_float(ub);
        int pix = valid ? (int)(HWSZ - 1 - (int)(w & 0x7FFFFULL)) : 0x7fffffff;
        int ys = pix >> 10;
        int xs = pix & (NW - 1);
        cxArr[b * TK + tid] = valid ? (float)xs : 1e9f;
        cyArr[b * TK + tid] = valid ? (float)ys : 1e9f;
        out_centers[(b * TK + tid) * 2 + 0] = (float)ys;
        out_centers[(b * TK + tid) * 2 + 1] = (float)xs;
        out_topvals[b * TK + tid] = valid ? v : -INFINITY;
    }
}

// ---------------- K5: instance assignment + LDS-aggregated seg_counts ----------------
__global__ __launch_bounds__(256) void k_assign(const float* __restrict__ reg,
                                                const int* __restrict__ segid,
                                                const float* __restrict__ cxArr,
                                                const float* __restrict__ cyArr,
                                                float* __restrict__ out_inst,
                                                int* __restrict__ instid,
                                                int* __restrict__ segcnt) {
    __shared__ float scx[TK];
    __shared__ float scy[TK];
    __shared__ int lcnt[TK * NC];
    int tid = threadIdx.x;
    int base = blockIdx.x * ACH;
    int b = base >> 19;
    if (tid < TK) {
        scx[tid] = cxArr[b * TK + tid];
        scy[tid] = cyArr[b * TK + tid];
    }
    for (int t = tid; t < TK * NC; t += 256) lcnt[t] = 0;
    __syncthreads();
    const float* r0 = reg + (size_t)b * 2 * HWSZ;
    const float* r1 = r0 + HWSZ;
    float px[4], py[4], bd[4];
    int bk[4];
#pragma unroll
    for (int it = 0; it < 4; it++) {
        int pix = (base & (HWSZ - 1)) + it * 256 + tid;
        int y = pix >> 10;
        int x = pix & (NW - 1);
        px[it] = __fsub_rn((float)(x + 1), r0[pix]);
        py[it] = __fsub_rn((float)(y + 1), r1[pix]);
        bd[it] = INFINITY; bk[it] = 0;
    }
#pragma unroll 4
    for (int k = 0; k < TK; k++) {
        float cx = scx[k];
        float cy = scy[k];
#pragma unroll
        for (int it = 0; it < 4; it++) {
            float dx = __fsub_rn(px[it], cx);
            float dy = __fsub_rn(py[it], cy);
            float d2 = __fadd_rn(__fmul_rn(dx, dx), __fmul_rn(dy, dy));
            if (d2 < bd[it]) { bd[it] = d2; bk[it] = k; }
        }
    }
#pragma unroll
    for (int it = 0; it < 4; it++) {
        int p = base + it * 256 + tid;
        int cls = segid[p];
        int thing = (cls >= 24) ? 1 : 0;
        int inst = (bk[it] + 1) * thing;
        out_inst[p] = (float)inst;
        instid[p] = inst;
        if (inst) atomicAdd(&lcnt[bk[it] * NC + cls], 1);
    }
    __syncthreads();
    for (int t = tid; t < TK * NC; t += 256) {
        int v = lcnt[t];
        if (v) atomicAdd(&segcnt[b * TK * NC + t], v);
    }
}

// ---------------- K6: per-instance class argmax + size; zero o_iprob ----------------
__global__ __launch_bounds__(256) void k_stats(const int* __restrict__ segcnt,
                                               float* __restrict__ out_icls,
                                               float* __restrict__ out_isize,
                                               float* __restrict__ out_iprob,
                                               int* __restrict__ icls,
                                               int* __restrict__ isize) {
    int t = blockIdx.x * 256 + threadIdx.x;
    if (t >= NB * TK) return;
    const int* row = segcnt + (size_t)t * NC;
    int total = 0; int bc = 0; int bv = -1;
#pragma unroll
    for (int c = 0; c < NC; c++) {
        int v = row[c];
        total += v;
        if (v > bv) { bv = v; bc = c; }
    }
    out_icls[t] = (float)bc;
    out_isize[t] = (float)total;
    out_iprob[t] = 0.f;                    // k_probsum atomically accumulates into this
    icls[t] = bc;
    isize[t] = total;
}

// ---------------- K7: prob sum of selected class -> o_iprob directly ----------------
__global__ __launch_bounds__(256) void k_probsum(const float* __restrict__ logits,
                                                 const int* __restrict__ instid,
                                                 const float* __restrict__ mArr,
                                                 const float* __restrict__ dArr,
                                                 const int* __restrict__ icls,
                                                 const int* __restrict__ isize,
                                                 float* __restrict__ out_iprob) {
    __shared__ float lps[TK];
    int tid = threadIdx.x;
    int base = blockIdx.x * ACH;
    int b = base >> 19;
    for (int t = tid; t < TK; t += 256) lps[t] = 0.f;
    __syncthreads();
#pragma unroll
    for (int it = 0; it < 4; it++) {
        int p = base + it * 256 + tid;
        int inst = instid[p];
        if (inst) {
            int pix = p & (HWSZ - 1);
            int c = icls[b * TK + inst - 1];
            float xv = logits[(size_t)(b * NC + c) * HWSZ + pix];
            float pr = __fdiv_rn(expf(__fsub_rn(xv, mArr[p])), dArr[p]);
            atomicAdd(&lps[inst - 1], pr);
        }
    }
    __syncthreads();
    for (int t = tid; t < TK; t += 256) {
        float s = lps[t];
        if (s != 0.f) {
            float sz = fmaxf((float)isize[b * TK + t], 1.0f);
            atomicAdd(&out_iprob[b * TK + t], s / sz);   // sum(s_i/n) == sum(s_i)/n ± ulp
        }
    }
}

// Host: replicate _circle_constants threshold exactly (NumPy pairwise sum, f32)
static float compute_thr_keep() {
    float cdm[121];
    int t = 0;
    for (int i = 0; i < 11; i++) {
        for (int j = 0; j < 11; j++) {
            float ox = (float)(j - 5), oy = (float)(i - 5);
            float cd = sqrtf(ox * ox + oy * oy);
            float cm = (cd <= 5.0f) ? 1.0f : 0.0f;
            cdm[t++] = cd * cm;
        }
    }
    float r[8];
    for (int k = 0; k < 8; k++) r[k] = cdm[k];
    int i = 8;
    for (; i < 121 - (121 % 8); i += 8)
        for (int k = 0; k < 8; k++) r[k] += cdm[i + k];
    float res = ((r[0] + r[1]) + (r[2] + r[3])) + ((r[4] + r[5]) + (r[6] + r[7]));
    for (; i < 121; i++) res += cdm[i];
    float thr = res / 81.0f;
    double kt = -(double)thr - 1.0;
    return (float)kt;
}

extern "C" void kernel_launch(void* const* d_in, const int* in_sizes, int n_in,
                              void* d_out, int out_size, void* d_ws, size_t ws_size,
                              hipStream_t stream) {
    const float* logits = (const float*)d_in[0];
    const float* reg    = (const float*)d_in[2];
    float* out = (float*)d_out;

    // output layout (all f32)
    float* o_inst    = out;                       // B*HW
    float* o_seg     = out + 1048576;             // B*HW
    float* o_centers = out + 2097152;             // B*TK*2
    float* o_topvals = out + 2097952;             // B*TK
    float* o_icls    = out + 2098352;             // B*TK
    float* o_iprob   = out + 2098752;             // B*TK
    float* o_isize   = out + 2099152;             // B*TK
    float* o_cmap    = out + 2099552;             // B*HW

    // workspace: keys (8B aligned) first, then contiguous zero-region, then rest
    u64* keys = (u64*)d_ws;                                   // NB*CAPC
    float* wsf = (float*)(keys + (size_t)NB * CAPC);
    size_t o = 0;
    int*   zreg    = (int*)(wsf + o); o += ZWORDS;            // [ccnt(8) | segcnt | probsum pad]
    int*   ccnt    = zreg;
    int*   segcnt  = zreg + 8;
    float* reg_pad = wsf + o; o += (size_t)NB * 2 * RPSZ;
    float* vote_pad= wsf + o; o += (size_t)NB * VPSZ;
    float* mArr    = wsf + o; o += (size_t)NB * HWSZ;
    float* dArr    = wsf + o; o += (size_t)NB * HWSZ;
    int*   segid   = (int*)(wsf + o); o += (size_t)NB * HWSZ;
    int*   instid  = (int*)(wsf + o); o += (size_t)NB * HWSZ;
    float* cxArr   = wsf + o; o += NB * TK;
    float* cyArr   = wsf + o; o += NB * TK;
    int*   icls    = (int*)(wsf + o); o += NB * TK;
    int*   isize   = (int*)(wsf + o); o += NB * TK;

    float thr_keep = compute_thr_keep();

    int gridPrep = (NB * 2 * RPSZ + 255) / 256;   // covers reg_pad; vote_pad fill < that
    int gridPix = (NB * HWSZ) / 256;   // 4096
    int gridRow = NB * NH;             // 1024: one image row per block, 4 px/thread
    int gridAgg = (NB * HWSZ) / ACH;   // 1024

    k_prep<<<gridPrep, 256, 0, stream>>>(reg, reg_pad, vote_pad);
    k_seg<<<gridPix, 256, 0, stream>>>(logits, o_seg, segid, mArr, dArr, zreg);
    k_vote<<<gridRow, 256, 0, stream>>>(reg_pad, vote_pad);
    k_pool<<<gridRow, 256, 0, stream>>>(vote_pad, o_cmap, keys, ccnt, thr_keep);
    k_topk<<<NB, 1024, 0, stream>>>(keys, ccnt, cxArr, cyArr, o_centers, o_topvals);
    k_assign<<<gridAgg, 256, 0, stream>>>(reg, segid, cxArr, cyArr, o_inst, instid, segcnt);
    k_stats<<<(NB * TK + 255) / 256, 256, 0, stream>>>(segcnt, o_icls, o_isize, o_iprob, icls, isize);
    k_probsum<<<gridAgg, 256, 0, stream>>>(logits, instid, mArr, dArr, icls, isize, o_iprob);
}

// Round 10
// 453.253 us; speedup vs baseline: 1.3584x; 1.0121x over previous
//
#include <hip/hip_runtime.h>
#include <cfloat>
#include <cmath>

#define NB 2
#define NC 34
#define NH 512
#define NW 1024
#define HWSZ (NH*NW)          // 524288 = 2^19
#define TK 200
#define CAPC 49152            // >= plausible 7x7 local-maxima count
#define CHUNK 8192            // LDS sort chunk (64KB)
#define ACH 1024              // pixels per block for aggregation kernels
#define ZWORDS (8 + NB*TK*NC + NB*TK)   // ccnt + segcnt + pad, contiguous

// padded layouts
#define PST 1040              // padded row stride (float4 alignment holds)
#define RPROWS 522            // reg pad: 5 top + 512 + 5 bottom
#define RPLEFT 8              // reg pad: left 8, right 8
#define VPROWS 518            // vote pad: 3 top + 512 + 3 bottom
#define VPLEFT 4              // vote pad: left 4, right 12
#define RPSZ (RPROWS*PST)
#define VPSZ (VPROWS*PST)

typedef unsigned long long u64;

// ---------------- K1: softmax stats + zero-fold + padded-buffer prep ----------------
__global__ __launch_bounds__(256) void k_seg(const float* __restrict__ logits,
                                             const float* __restrict__ reg,
                                             float* __restrict__ segmap_out,
                                             float* __restrict__ mArr,
                                             float* __restrict__ dArr,
                                             float* __restrict__ reg_pad,
                                             float* __restrict__ vote_pad,
                                             int* __restrict__ zreg) {
    int p = blockIdx.x * 256 + threadIdx.x;
    if (p < ZWORDS) zreg[p] = 0;
    // prep reg_pad (zero-padded reg) and vote_pad (-inf border), grid-stride
    for (int t = p; t < NB * 2 * RPSZ; t += NB * HWSZ) {
        int c = t % PST;
        int rest = t / PST;
        int r = rest % RPROWS;
        int bc = rest / RPROWS;            // b*2 + ch
        int rr = r - 5, cc = c - RPLEFT;
        float v = 0.f;
        if (rr >= 0 && rr < NH && cc >= 0 && cc < NW)
            v = reg[(size_t)bc * HWSZ + rr * NW + cc];
        reg_pad[t] = v;
    }
    for (int t = p; t < NB * VPSZ; t += NB * HWSZ) vote_pad[t] = -INFINITY;
    if (p >= NB * HWSZ) return;
    int b = p >> 19;
    int pix = p & (HWSZ - 1);
    const float* base = logits + (size_t)b * NC * HWSZ + pix;
    float v[NC];
#pragma unroll
    for (int c = 0; c < NC; c++) v[c] = base[(size_t)c * HWSZ];
    float m = -FLT_MAX; int bc = 0;
#pragma unroll
    for (int c = 0; c < NC; c++) { if (v[c] > m) { m = v[c]; bc = c; } }
    float den = 0.f;
#pragma unroll
    for (int c = 0; c < NC; c++) den += expf(v[c] - m);
    segmap_out[p] = (float)bc;
    mArr[p] = m;
    dArr[p] = den;
}

#define GETC(f, idx) (((idx)&3)==0 ? f[(idx)>>2].x : ((idx)&3)==1 ? f[(idx)>>2].y : \
                      ((idx)&3)==2 ? f[(idx)>>2].z : f[(idx)>>2].w)

// ---------------- K2: vote map, XCD-swizzled rows, branch-free aligned loads ----------------
// y swizzle: XCD = blk%8 owns a contiguous 64-row band -> reg rows reused from
// that XCD's L2 (working set ~2.5 MB < 4 MB). Exact f32 term order preserved.
__global__ __launch_bounds__(256, 4) void k_vote(const float* __restrict__ reg_pad,
                                                 float* __restrict__ vote_pad) {
    int tid = threadIdx.x;
    int blk = blockIdx.x;
    int b = blk >> 9;
    int q = blk & 511;
    int y = ((q & 7) << 6) | (q >> 3);    // bijection: XCD-contiguous row bands
    int xb = tid << 2;
    const float* rp0 = reg_pad + (size_t)(b * 2 + 0) * RPSZ;
    const float* rp1 = reg_pad + (size_t)(b * 2 + 1) * RPSZ;
    float a0 = 0.f, a1 = 0.f, a2 = 0.f, a3 = 0.f;

    float4 fA0[5], fA1[5], fB0[5], fB1[5];

    auto loadwin = [&](int i, float4* f0, float4* f1) {
        const float* p0 = rp0 + (size_t)(y + i) * PST + xb;
        const float* p1 = rp1 + (size_t)(y + i) * PST + xb;
#pragma unroll
        for (int t = 0; t < 5; t++) f0[t] = *(const float4*)(p0 + 4 * t);
#pragma unroll
        for (int t = 0; t < 5; t++) f1[t] = *(const float4*)(p1 + 4 * t);
    };

    auto compute = [&](int i, const float4* f0, const float4* f1) {
        int d = i - 5;
        int ad = d < 0 ? -d : d;
        int w = (int)sqrtf((float)(25 - ad * ad));   // exact for {0,9,16,21,24,25}
        int lo = 5 - w, hi = 5 + w;
        float di = (float)d;
#pragma unroll
        for (int j = 0; j < 11; j++) {
            if (j < lo || j > hi) continue;
            float dj = (float)(j - 5);
            float dx, dy, ss;
            dx = __fsub_rn(dj, GETC(f0, j+3)); dy = __fsub_rn(di, GETC(f1, j+3));
            ss = __fadd_rn(__fmul_rn(dx,dx), __fmul_rn(dy,dy));
            a0 = __fadd_rn(a0, sqrtf(ss));
            dx = __fsub_rn(dj, GETC(f0, j+4)); dy = __fsub_rn(di, GETC(f1, j+4));
            ss = __fadd_rn(__fmul_rn(dx,dx), __fmul_rn(dy,dy));
            a1 = __fadd_rn(a1, sqrtf(ss));
            dx = __fsub_rn(dj, GETC(f0, j+5)); dy = __fsub_rn(di, GETC(f1, j+5));
            ss = __fadd_rn(__fmul_rn(dx,dx), __fmul_rn(dy,dy));
            a2 = __fadd_rn(a2, sqrtf(ss));
            dx = __fsub_rn(dj, GETC(f0, j+6)); dy = __fsub_rn(di, GETC(f1, j+6));
            ss = __fadd_rn(__fmul_rn(dx,dx), __fmul_rn(dy,dy));
            a3 = __fadd_rn(a3, sqrtf(ss));
        }
    };

    loadwin(0, fA0, fA1);
#pragma unroll 1
    for (int i = 0; i < 10; i += 2) {
        loadwin(i + 1, fB0, fB1);
        compute(i, fA0, fA1);
        loadwin(i + 2, fA0, fA1);
        compute(i + 1, fB0, fB1);
    }
    compute(10, fA0, fA1);

    float4 vv;
    vv.x = __fsub_rn(-__fdiv_rn(a0, 81.0f), 1.0f);
    vv.y = __fsub_rn(-__fdiv_rn(a1, 81.0f), 1.0f);
    vv.z = __fsub_rn(-__fdiv_rn(a2, 81.0f), 1.0f);
    vv.w = __fsub_rn(-__fdiv_rn(a3, 81.0f), 1.0f);
    *(float4*)(vote_pad + (size_t)b * VPSZ + (size_t)(y + 3) * PST + (xb + VPLEFT)) = vv;
}

// ---------------- K3: 7x7 max pool, XCD-swizzled, branch-free ----------------
__global__ __launch_bounds__(256) void k_pool(const float* __restrict__ vote_pad,
                                              float* __restrict__ cmap_out,
                                              u64* __restrict__ keys,
                                              int* __restrict__ ccnt,
                                              float thr_keep) {
    int tid = threadIdx.x;
    int blk = blockIdx.x;
    int b = blk >> 9;
    int q = blk & 511;
    int y = ((q & 7) << 6) | (q >> 3);
    int xb = tid << 2;
    const float* vp = vote_pad + (size_t)b * VPSZ;
    float cm[10];
#pragma unroll
    for (int t = 0; t < 10; t++) cm[t] = -INFINITY;
    float vv[4];
#pragma unroll 1
    for (int dy = -3; dy <= 3; dy++) {
        const float* row = vp + (size_t)(y + dy + 3) * PST + xb;   // real cols [xb-4, xb+8)
        float4 A = *(const float4*)(row);
        float4 Bq = *(const float4*)(row + 4);
        float4 Cq = *(const float4*)(row + 8);
        float L[12] = {A.x,A.y,A.z,A.w, Bq.x,Bq.y,Bq.z,Bq.w, Cq.x,Cq.y,Cq.z,Cq.w};
#pragma unroll
        for (int t = 0; t < 10; t++) cm[t] = fmaxf(cm[t], L[t + 1]);
        if (dy == 0) { vv[0]=L[4]; vv[1]=L[5]; vv[2]=L[6]; vv[3]=L[7]; }
    }
    int pix = y * NW + xb;
    float cmap[4];
#pragma unroll
    for (int k = 0; k < 4; k++) {
        float mx = cm[k];
#pragma unroll
        for (int u = 1; u < 7; u++) mx = fmaxf(mx, cm[k+u]);
        bool keep = (mx == vv[k]) && (vv[k] > thr_keep);
        cmap[k] = keep ? vv[k] : 0.0f;
        if (keep) {
            int pos = atomicAdd(&ccnt[b], 1);
            if (pos < CAPC) {
                unsigned u = __float_as_uint(vv[k]);
                unsigned ou = ((int)u < 0) ? ~u : (u | 0x80000000u);
                keys[(size_t)b * CAPC + pos] = ((u64)ou << 19) | (u64)(HWSZ - 1 - (pix + k));
            }
        }
    }
    *(float4*)(cmap_out + b * HWSZ + pix) = make_float4(cmap[0],cmap[1],cmap[2],cmap[3]);
}

// Descending bitonic sort of a[0..np2) in LDS. Keys unique (or 0) -> deterministic.
__device__ inline void bitonic_desc(u64* a, int np2, int tid, int T) {
    for (int k = 2; k <= np2; k <<= 1) {
        for (int j = k >> 1; j > 0; j >>= 1) {
            for (int i = tid; i < np2; i += T) {
                int ixj = i ^ j;
                if (ixj > i) {
                    u64 x = a[i], y = a[ixj];
                    bool up = ((i & k) == 0);
                    if (up ? (x < y) : (x > y)) { a[i] = y; a[ixj] = x; }
                }
            }
            __syncthreads();
        }
    }
}

// ---------------- K4: top-200 via LDS bitonic sort ----------------
__global__ __launch_bounds__(1024) void k_topk(const u64* __restrict__ keys_g,
                                               const int* __restrict__ ccnt,
                                               float* __restrict__ cxArr,
                                               float* __restrict__ cyArr,
                                               float* __restrict__ out_centers,
                                               float* __restrict__ out_topvals) {
    __shared__ u64 sk[CHUNK];
    __shared__ u64 cur[512];
    const int T = 1024;
    int b = blockIdx.x;
    int tid = threadIdx.x;
    int n = ccnt[b];
    if (n > CAPC) n = CAPC;
    const u64* Kg = keys_g + (size_t)b * CAPC;
    int nch = (n + CHUNK - 1) / CHUNK;
    if (nch < 1) nch = 1;
    if (tid < 512) cur[tid] = 0;
    __syncthreads();
    for (int ch = 0; ch < nch; ch++) {
        int off = ch * CHUNK;
        int len = n - off; if (len < 0) len = 0; if (len > CHUNK) len = CHUNK;
        int np2 = 256; while (np2 < len) np2 <<= 1;
        for (int c = tid; c < np2; c += T) sk[c] = (c < len) ? Kg[off + c] : 0;
        __syncthreads();
        bitonic_desc(sk, np2, tid, T);
        if (ch == 0) {
            if (tid < TK) cur[tid] = sk[tid];
            __syncthreads();
        } else {
            if (tid < TK) cur[TK + tid] = sk[tid];
            else if (tid < 512) { if (tid >= 2 * TK) cur[tid] = 0; }
            __syncthreads();
            bitonic_desc(cur, 512, tid, T);
        }
    }
    if (tid < TK) {
        u64 w = cur[tid];
        bool valid = (w != 0ULL);
        unsigned ou = (unsigned)(w >> 19);
        unsigned ub = (ou & 0x80000000u) ? (ou & 0x7FFFFFFFu) : ~ou;
        float v = __uint_as_float(ub);
        int pix = valid ? (int)(HWSZ - 1 - (int)(w & 0x7FFFFULL)) : 0x7fffffff;
        int ys = pix >> 10;
        int xs = pix & (NW - 1);
        cxArr[b * TK + tid] = valid ? (float)xs : 1e9f;
        cyArr[b * TK + tid] = valid ? (float)ys : 1e9f;
        out_centers[(b * TK + tid) * 2 + 0] = (float)ys;
        out_centers[(b * TK + tid) * 2 + 1] = (float)xs;
        out_topvals[b * TK + tid] = valid ? v : -INFINITY;
    }
}

// ---------------- K5: instance assignment, 4 consecutive px/thread, float4 I/O ----------------
__global__ __launch_bounds__(256) void k_assign(const float* __restrict__ reg,
                                                const float* __restrict__ segmap,
                                                const float* __restrict__ cxArr,
                                                const float* __restrict__ cyArr,
                                                float* __restrict__ out_inst,
                                                int* __restrict__ segcnt) {
    __shared__ float scx[TK];
    __shared__ float scy[TK];
    __shared__ int lcnt[TK * NC];
    int tid = threadIdx.x;
    int base = blockIdx.x * ACH;
    int b = base >> 19;
    if (tid < TK) {
        scx[tid] = cxArr[b * TK + tid];
        scy[tid] = cyArr[b * TK + tid];
    }
    for (int t = tid; t < TK * NC; t += 256) lcnt[t] = 0;
    __syncthreads();
    const float* r0 = reg + (size_t)b * 2 * HWSZ;
    const float* r1 = r0 + HWSZ;
    int pix0 = (base & (HWSZ - 1)) + tid * 4;      // 4 consecutive px, same row
    int y = pix0 >> 10;
    int x0 = pix0 & (NW - 1);
    float4 rx = *(const float4*)(r0 + pix0);
    float4 ry = *(const float4*)(r1 + pix0);
    float px[4], py[4], bd[4];
    int bk[4];
    px[0] = __fsub_rn((float)(x0 + 1), rx.x); py[0] = __fsub_rn((float)(y + 1), ry.x);
    px[1] = __fsub_rn((float)(x0 + 2), rx.y); py[1] = __fsub_rn((float)(y + 1), ry.y);
    px[2] = __fsub_rn((float)(x0 + 3), rx.z); py[2] = __fsub_rn((float)(y + 1), ry.z);
    px[3] = __fsub_rn((float)(x0 + 4), rx.w); py[3] = __fsub_rn((float)(y + 1), ry.w);
#pragma unroll
    for (int it = 0; it < 4; it++) { bd[it] = INFINITY; bk[it] = 0; }
#pragma unroll 4
    for (int k = 0; k < TK; k++) {
        float cx = scx[k];
        float cy = scy[k];
#pragma unroll
        for (int it = 0; it < 4; it++) {
            float dx = __fsub_rn(px[it], cx);
            float dy = __fsub_rn(py[it], cy);
            float d2 = __fadd_rn(__fmul_rn(dx, dx), __fmul_rn(dy, dy));
            if (d2 < bd[it]) { bd[it] = d2; bk[it] = k; }
        }
    }
    float4 sm = *(const float4*)(segmap + base + tid * 4);
    float scls[4] = {sm.x, sm.y, sm.z, sm.w};
    float oi[4];
#pragma unroll
    for (int it = 0; it < 4; it++) {
        int cls = (int)scls[it];
        int thing = (cls >= 24) ? 1 : 0;
        int inst = (bk[it] + 1) * thing;
        oi[it] = (float)inst;
        if (inst) atomicAdd(&lcnt[bk[it] * NC + cls], 1);
    }
    *(float4*)(out_inst + base + tid * 4) = make_float4(oi[0], oi[1], oi[2], oi[3]);
    __syncthreads();
    for (int t = tid; t < TK * NC; t += 256) {
        int v = lcnt[t];
        if (v) atomicAdd(&segcnt[b * TK * NC + t], v);
    }
}

// ---------------- K6: per-instance class argmax + size; zero o_iprob ----------------
__global__ __launch_bounds__(256) void k_stats(const int* __restrict__ segcnt,
                                               float* __restrict__ out_icls,
                                               float* __restrict__ out_isize,
                                               float* __restrict__ out_iprob,
                                               int* __restrict__ icls,
                                               int* __restrict__ isize) {
    int t = blockIdx.x * 256 + threadIdx.x;
    if (t >= NB * TK) return;
    const int* row = segcnt + (size_t)t * NC;
    int total = 0; int bc = 0; int bv = -1;
#pragma unroll
    for (int c = 0; c < NC; c++) {
        int v = row[c];
        total += v;
        if (v > bv) { bv = v; bc = c; }
    }
    out_icls[t] = (float)bc;
    out_isize[t] = (float)total;
    out_iprob[t] = 0.f;
    icls[t] = bc;
    isize[t] = total;
}

// ---------------- K7: prob sum of selected class -> o_iprob ----------------
__global__ __launch_bounds__(256) void k_probsum(const float* __restrict__ logits,
                                                 const float* __restrict__ inst_f,
                                                 const float* __restrict__ mArr,
                                                 const float* __restrict__ dArr,
                                                 const int* __restrict__ icls,
                                                 const int* __restrict__ isize,
                                                 float* __restrict__ out_iprob) {
    __shared__ float lps[TK];
    int tid = threadIdx.x;
    int base = blockIdx.x * ACH;
    int b = base >> 19;
    for (int t = tid; t < TK; t += 256) lps[t] = 0.f;
    __syncthreads();
    int p0 = base + tid * 4;
    float4 fi = *(const float4*)(inst_f + p0);
    float4 fm = *(const float4*)(mArr + p0);
    float4 fd = *(const float4*)(dArr + p0);
    float insts[4] = {fi.x, fi.y, fi.z, fi.w};
    float ms[4] = {fm.x, fm.y, fm.z, fm.w};
    float ds[4] = {fd.x, fd.y, fd.z, fd.w};
#pragma unroll
    for (int it = 0; it < 4; it++) {
        int inst = (int)insts[it];
        if (inst) {
            int p = p0 + it;
            int pix = p & (HWSZ - 1);
            int c = icls[b * TK + inst - 1];
            float xv = logits[(size_t)(b * NC + c) * HWSZ + pix];
            float pr = __fdiv_rn(expf(__fsub_rn(xv, ms[it])), ds[it]);
            atomicAdd(&lps[inst - 1], pr);
        }
    }
    __syncthreads();
    for (int t = tid; t < TK; t += 256) {
        float s = lps[t];
        if (s != 0.f) {
            float sz = fmaxf((float)isize[b * TK + t], 1.0f);
            atomicAdd(&out_iprob[b * TK + t], s / sz);
        }
    }
}

// Host: replicate _circle_constants threshold exactly (NumPy pairwise sum, f32)
static float compute_thr_keep() {
    float cdm[121];
    int t = 0;
    for (int i = 0; i < 11; i++) {
        for (int j = 0; j < 11; j++) {
            float ox = (float)(j - 5), oy = (float)(i - 5);
            float cd = sqrtf(ox * ox + oy * oy);
            float cm = (cd <= 5.0f) ? 1.0f : 0.0f;
            cdm[t++] = cd * cm;
        }
    }
    float r[8];
    for (int k = 0; k < 8; k++) r[k] = cdm[k];
    int i = 8;
    for (; i < 121 - (121 % 8); i += 8)
        for (int k = 0; k < 8; k++) r[k] += cdm[i + k];
    float res = ((r[0] + r[1]) + (r[2] + r[3])) + ((r[4] + r[5]) + (r[6] + r[7]));
    for (; i < 121; i++) res += cdm[i];
    float thr = res / 81.0f;
    double kt = -(double)thr - 1.0;
    return (float)kt;
}

extern "C" void kernel_launch(void* const* d_in, const int* in_sizes, int n_in,
                              void* d_out, int out_size, void* d_ws, size_t ws_size,
                              hipStream_t stream) {
    const float* logits = (const float*)d_in[0];
    const float* reg    = (const float*)d_in[2];
    float* out = (float*)d_out;

    // output layout (all f32)
    float* o_inst    = out;                       // B*HW
    float* o_seg     = out + 1048576;             // B*HW
    float* o_centers = out + 2097152;             // B*TK*2
    float* o_topvals = out + 2097952;             // B*TK
    float* o_icls    = out + 2098352;             // B*TK
    float* o_iprob   = out + 2098752;             // B*TK
    float* o_isize   = out + 2099152;             // B*TK
    float* o_cmap    = out + 2099552;             // B*HW

    // workspace: keys (8B aligned) first, then contiguous zero-region, then rest
    u64* keys = (u64*)d_ws;                                   // NB*CAPC
    float* wsf = (float*)(keys + (size_t)NB * CAPC);
    size_t o = 0;
    int*   zreg    = (int*)(wsf + o); o += ZWORDS;            // [ccnt(8) | segcnt]
    int*   ccnt    = zreg;
    int*   segcnt  = zreg + 8;
    float* reg_pad = wsf + o; o += (size_t)NB * 2 * RPSZ;
    float* vote_pad= wsf + o; o += (size_t)NB * VPSZ;
    float* mArr    = wsf + o; o += (size_t)NB * HWSZ;
    float* dArr    = wsf + o; o += (size_t)NB * HWSZ;
    float* cxArr   = wsf + o; o += NB * TK;
    float* cyArr   = wsf + o; o += NB * TK;
    int*   icls    = (int*)(wsf + o); o += NB * TK;
    int*   isize   = (int*)(wsf + o); o += NB * TK;

    float thr_keep = compute_thr_keep();

    int gridPix = (NB * HWSZ) / 256;   // 4096
    int gridRow = NB * NH;             // 1024
    int gridAgg = (NB * HWSZ) / ACH;   // 1024

    k_seg<<<gridPix, 256, 0, stream>>>(logits, reg, o_seg, mArr, dArr, reg_pad, vote_pad, zreg);
    k_vote<<<gridRow, 256, 0, stream>>>(reg_pad, vote_pad);
    k_pool<<<gridRow, 256, 0, stream>>>(vote_pad, o_cmap, keys, ccnt, thr_keep);
    k_topk<<<NB, 1024, 0, stream>>>(keys, ccnt, cxArr, cyArr, o_centers, o_topvals);
    k_assign<<<gridAgg, 256, 0, stream>>>(reg, o_seg, cxArr, cyArr, o_inst, segcnt);
    k_stats<<<(NB * TK + 255) / 256, 256, 0, stream>>>(segcnt, o_icls, o_isize, o_iprob, icls, isize);
    k_probsum<<<gridAgg, 256, 0, stream>>>(logits, o_inst, mArr, dArr, icls, isize, o_iprob);
}